// Round 1
// baseline (253.201 us; speedup 1.0000x reference)
//
#include <hip/hip_runtime.h>
#include <hip/hip_bf16.h>
#include <math.h>

#define N_CELL 76
#define N_DRUG 764
#define N_ITEM 840
#define BATCH  4096

// ws layout (byte offsets)
#define POOL2H_B 0u
#define POOL2L_B 13762560u
#define WHI_B    27525120u
#define WLO_B    28573696u
#define XFC_B    29622272u
#define ITEM_B   29837312u
#define EMB_B    30052352u
#define V_B      30267392u
#define LOSS_B   30306304u
#define CNT_B    30306368u

typedef short bh8 __attribute__((ext_vector_type(8)));
typedef short bh4 __attribute__((ext_vector_type(4)));
typedef float f32x4 __attribute__((ext_vector_type(4)));

static __device__ inline unsigned short f2bf(float f) {
  union { float f; unsigned u; } v; v.f = f;
  unsigned r = v.u + 0x7FFFu + ((v.u >> 16) & 1u);  // RNE (no NaN inputs here)
  return (unsigned short)(r >> 16);
}
static __device__ inline float bf2f(unsigned short h) {
  union { unsigned u; float f; } v; v.u = ((unsigned)h) << 16;
  return v.f;
}
// lo residual via truncation (residual <= 2^-9|a|, trunc err <= 2^-17|a|)
static __device__ inline unsigned short f2bf_lo(float f, unsigned short h) {
  union { float f; unsigned u; } a; a.f = f - bf2f(h);
  return (unsigned short)(a.u >> 16);
}

union BH8U { bh8 v; struct { bh4 lo, hi; } s; };

// ---------------- fused conv1+pool1+conv2+pool2 (quarter blocks) ----------------
// Block = conv2-quarter (8 pool2 rows). Computes its own 18-row pool1 halo tile
// via conv1 MFMA (12.5% redundant rows), keeps pool1 in LDS split-bf16 — no
// pool1 HBM round trip. Blocks with blockIdx.y>=840 do the out_w cast + zeroing.
// LDS: input stage 38x34x4 ush x2 = 20.7KB, pool1 tile 18x66x4 ush x2 = 19KB.
__global__ __launch_bounds__(256) void k_conv12(
    const float* __restrict__ cell_pre, const float* __restrict__ drug_pre,
    const float* __restrict__ w1, const float* __restrict__ b1,
    const float* __restrict__ w2, const float* __restrict__ b2,
    const float* __restrict__ out_w,
    unsigned short* __restrict__ pool2h, unsigned short* __restrict__ pool2l,
    unsigned short* __restrict__ whi, unsigned short* __restrict__ wlo,
    float* __restrict__ xfc, float* __restrict__ loss, unsigned* __restrict__ cnt) {
  __shared__ unsigned short slh[38 * 34 * 4];
  __shared__ unsigned short sll[38 * 34 * 4];
  __shared__ unsigned short p1h[18 * 66 * 4];
  __shared__ unsigned short p1l[18 * 66 * 4];
  int n = blockIdx.y;
  int tid = threadIdx.x;
  if (n >= 840) {
    // ---- cast/zero blocks: 5 y-rows x 4 = 20 blocks, 5120 threads ----
    int cb = (n - 840) * 4 + blockIdx.x;
    int gid = cb * 256 + tid;  // 0..5119
    if (gid == 0) { *loss = 0.f; *cnt = 0u; }
    for (int i = gid; i < 13440; i += 5120)  // zero xfc (840*64 f32)
      ((float4*)xfc)[i] = make_float4(0.f, 0.f, 0.f, 0.f);
    for (int i = gid; i < 131072; i += 5120) {  // split-cast out_w
      float4 v = ((const float4*)out_w)[i];
      ushort4 h, l;
      h.x = f2bf(v.x); l.x = f2bf(v.x - bf2f(h.x));
      h.y = f2bf(v.y); l.y = f2bf(v.y - bf2f(h.y));
      h.z = f2bf(v.z); l.z = f2bf(v.z - bf2f(h.z));
      h.w = f2bf(v.w); l.w = f2bf(v.w - bf2f(h.w));
      ((ushort4*)whi)[i] = h;
      ((ushort4*)wlo)[i] = l;
    }
    return;
  }
  int qt = blockIdx.x;  // conv2-quarter 0..3
  // ---- stage input rows iy = 32*qt - 3 + lr, lr = 0..37 ----
  const float4* src = (const float4*)((n < N_CELL) ? (cell_pre + (size_t)n * 16384)
                                                   : (drug_pre + (size_t)(n - N_CELL) * 16384));
  for (int i = tid; i < 38 * 32; i += 256) {
    int lr = i >> 5, g = i & 31;
    int iy = qt * 32 - 3 + lr;
    float4 v = make_float4(0.f, 0.f, 0.f, 0.f);
    if (iy >= 0 && iy < 128) v = src[iy * 32 + g];
    ushort4 h, l;
    h.x = f2bf(v.x); l.x = f2bf_lo(v.x, h.x);
    h.y = f2bf(v.y); l.y = f2bf_lo(v.y, h.y);
    h.z = f2bf(v.z); l.z = f2bf_lo(v.z, h.z);
    h.w = f2bf(v.w); l.w = f2bf_lo(v.w, h.w);
    ((ushort4*)slh)[lr * 34 + g + 1] = h;
    ((ushort4*)sll)[lr * 34 + g + 1] = l;
  }
  if (tid < 76) {  // input x-pad
    int lr = tid >> 1, g = (tid & 1) ? 33 : 0;
    ushort4 z = make_ushort4(0, 0, 0, 0);
    ((ushort4*)slh)[lr * 34 + g] = z;
    ((ushort4*)sll)[lr * 34 + g] = z;
  }
  if (tid < 36) {  // pool1-tile x-pad (cols 0 and 65)
    int r = tid >> 1, c = (tid & 1) ? 65 : 0;
    ushort4 z = make_ushort4(0, 0, 0, 0);
    ((ushort4*)p1h)[r * 66 + c] = z;
    ((ushort4*)p1l)[r * 66 + c] = z;
  }
  int wv = tid >> 6;
  int lane = tid & 63;
  int ml = lane & 15, q = lane >> 4;

  // ---- conv1 B fragments (lane = col ml; k = q*8+j; r=q, w=j) ----
  int oc = ml & 3, yv1 = (ml >> 2) & 1, hi = ml >> 3;
  float bb = b1[oc];
  bh8 BhE, BlE, BhO, BlO;
  {
    int kr = q - yv1;
    bool krok = (kr >= 0 && kr <= 2);
#pragma unroll
    for (int j = 0; j < 8; ++j) {
      float ve = 0.f, vo = 0.f;
      if (krok) {
        int kse = j - 3 - 2 * hi;   // even phases 0/2
        int kso = j - 2 * hi;       // odd  phases 1/3
        if (kse >= 0 && kse <= 2) ve = w1[oc * 9 + kr * 3 + kse];
        if (kso >= 0 && kso <= 2) vo = w1[oc * 9 + kr * 3 + kso];
      }
      unsigned short he = f2bf(ve), ho = f2bf(vo);
      BhE[j] = (short)he; BlE[j] = (short)f2bf_lo(ve, he);
      BhO[j] = (short)ho; BlO[j] = (short)f2bf_lo(vo, ho);
    }
  }
  // ---- conv2 B fragments ----
  int oc_b = ml & 7, yv2 = ml >> 3;
  bh8 Bh2[2], Bl2[2];
#pragma unroll
  for (int ch = 0; ch < 2; ++ch) {
#pragma unroll
    for (int j = 0; j < 8; ++j) {
      int kg = ch * 32 + q * 8 + j;
      float v = 0.f;
      if (kg < 48) {
        int r = kg / 12, rem = kg - r * 12;
        int ks = rem >> 2, ic = rem & 3;
        int kr = r - yv2;
        if (kr >= 0 && kr <= 2) v = w2[(oc_b * 4 + ic) * 9 + kr * 3 + ks];
      } else if (kg == 48) {
        v = b2[oc_b];
      }
      unsigned short h = f2bf(v);
      Bh2[ch][j] = (short)h;
      Bl2[ch][j] = (short)f2bf_lo(v, h);
    }
  }
  // conv2 A-offsets
  int c0 = 2 * q, c1 = 2 * q + 1;
  int c2 = 8 + 2 * q, c3 = 9 + 2 * q;
  if (c2 > 11) { c2 = 8; c3 = 9; }
  int r0 = (c0 * 86) >> 8, s0 = c0 - 3 * r0;
  int r1 = (c1 * 86) >> 8, s1 = c1 - 3 * r1;
  int r2 = (c2 * 86) >> 8, s2 = c2 - 3 * r2;
  int r3 = (c3 * 86) >> 8, s3 = c3 - 3 * r3;
  int x2 = (wv & 3) << 4;
  int off0 = r0 * 66 + x2 + ml + s0;
  int off1 = r1 * 66 + x2 + ml + s1;
  int off2 = r2 * 66 + x2 + ml + s2;
  int off3 = r3 * 66 + x2 + ml + s3;
  __syncthreads();

  // ---- conv1 phase: wave = (wv&1) x-half (32 px) x 9 tile rows ----
  int x0 = (wv & 1) * 16;
  int rbase = (wv >> 1) * 9;
  int Lb = x0 + ml;
  const bh4* lh4 = (const bh4*)slh;
  const bh4* ll4 = (const bh4*)sll;
#pragma unroll 1
  for (int ii = 0; ii < 9; ++ii) {
    int i = rbase + ii;          // pool1-tile row 0..17
    int base = (2 * i + q) * 34 + Lb;
    bh4 g0h = lh4[base], g1h = lh4[base + 1], g2h = lh4[base + 2];
    bh4 g0l = ll4[base], g1l = ll4[base + 1], g2l = ll4[base + 2];
    BH8U aeh, ael, aoh, aol;
    aeh.s.lo = g0h; aeh.s.hi = g1h;
    ael.s.lo = g0l; ael.s.hi = g1l;
    aoh.s.lo = g1h; aoh.s.hi = g2h;
    aol.s.lo = g1l; aol.s.hi = g2l;
    f32x4 de = {0.f, 0.f, 0.f, 0.f}, dd = de;
    de = __builtin_amdgcn_mfma_f32_16x16x32_bf16(aeh.v, BhE, de, 0, 0, 0);
    de = __builtin_amdgcn_mfma_f32_16x16x32_bf16(aeh.v, BlE, de, 0, 0, 0);
    de = __builtin_amdgcn_mfma_f32_16x16x32_bf16(ael.v, BhE, de, 0, 0, 0);
    dd = __builtin_amdgcn_mfma_f32_16x16x32_bf16(aoh.v, BhO, dd, 0, 0, 0);
    dd = __builtin_amdgcn_mfma_f32_16x16x32_bf16(aoh.v, BlO, dd, 0, 0, 0);
    dd = __builtin_amdgcn_mfma_f32_16x16x32_bf16(aol.v, BhO, dd, 0, 0, 0);
    int pr = qt * 16 - 1 + i;    // global pool1 row (halo rows may be out of range)
    bool inr = (pr >= 0 && pr < 64);
#pragma unroll
    for (int r = 0; r < 4; ++r) {
      float t = fmaxf(de[r], dd[r]);        // x-pool
      float t2 = __shfl_xor(t, 4);          // y-pool partner
      if (yv1 == 0) {
        float val = fmaxf(fmaxf(t, t2) + bb, 0.f);
        if (!inr) val = 0.f;                // conv2 zero-padding rows
        unsigned short h = f2bf(val);
        unsigned short l = f2bf_lo(val, h);
        int px = 2 * (x0 + q * 4 + r) + hi;
        int idx = (i * 66 + px + 1) * 4 + oc;
        p1h[idx] = h; p1l[idx] = l;
      }
    }
  }
  __syncthreads();

  // ---- conv2 phase (identical math to previous k_conv2) ----
  const bh4* ph4 = (const bh4*)p1h;
  const bh4* pl4 = (const bh4*)p1l;
#pragma unroll 1
  for (int rp = 0; rp < 8; ++rp) {
    int base2 = 2 * rp * 66;
    BH8U ah0, al0, ah1, al1;
    ah0.s.lo = ph4[base2 + off0]; ah0.s.hi = ph4[base2 + off1];
    al0.s.lo = pl4[base2 + off0]; al0.s.hi = pl4[base2 + off1];
    if (q < 2) {
      ah1.s.lo = ph4[base2 + off2]; ah1.s.hi = ph4[base2 + off3];
      al1.s.lo = pl4[base2 + off2]; al1.s.hi = pl4[base2 + off3];
    } else {
#pragma unroll
      for (int j = 0; j < 8; ++j) { ah1.v[j] = 0; al1.v[j] = 0; }
      if (q == 2) ah1.v[0] = (short)0x3F80;  // bf16 1.0 -> bias row k=48
    }
    f32x4 accA = {0.f, 0.f, 0.f, 0.f}, accB = accA;
    accA = __builtin_amdgcn_mfma_f32_16x16x32_bf16(ah0.v, Bh2[0], accA, 0, 0, 0);
    accA = __builtin_amdgcn_mfma_f32_16x16x32_bf16(ah0.v, Bl2[0], accA, 0, 0, 0);
    accA = __builtin_amdgcn_mfma_f32_16x16x32_bf16(al0.v, Bh2[0], accA, 0, 0, 0);
    accB = __builtin_amdgcn_mfma_f32_16x16x32_bf16(ah1.v, Bh2[1], accB, 0, 0, 0);
    accB = __builtin_amdgcn_mfma_f32_16x16x32_bf16(ah1.v, Bl2[1], accB, 0, 0, 0);
    accB = __builtin_amdgcn_mfma_f32_16x16x32_bf16(al1.v, Bh2[1], accB, 0, 0, 0);
    float d0 = accA[0] + accB[0], d1 = accA[1] + accB[1];
    float d2 = accA[2] + accB[2], d3 = accA[3] + accB[3];
    float m0 = fmaxf(d0, d1), m1 = fmaxf(d2, d3);
    float o0 = __shfl_xor(m0, 8), o1 = __shfl_xor(m1, 8);
    m0 = fmaxf(fmaxf(m0, o0), 0.f);
    m1 = fmaxf(fmaxf(m1, o1), 0.f);
    if (yv2 == 0) {
      unsigned short h0 = f2bf(m0), h1 = f2bf(m1);
      unsigned short l0 = f2bf(m0 - bf2f(h0)), l1 = f2bf(m1 - bf2f(h1));
      int PR = qt * 8 + rp;
      unsigned ui = (unsigned)n * 4096u + (unsigned)oc_b * 512u +
                    (unsigned)PR * 16u + (unsigned)(x2 >> 2) + (unsigned)q;
      ((unsigned*)pool2h)[ui] = (unsigned)h0 | ((unsigned)h1 << 16);
      ((unsigned*)pool2l)[ui] = (unsigned)l0 | ((unsigned)l1 << 16);
    }
  }
}

// ---------------- FC: split-bf16 MFMA GEMM, M=840 N=64, K chunks of 256 ----------------
__global__ __launch_bounds__(64) void k_fc(
    const unsigned short* __restrict__ pool2h, const unsigned short* __restrict__ pool2l,
    const unsigned short* __restrict__ whi, const unsigned short* __restrict__ wlo,
    float* __restrict__ xfc) {
  int mt = blockIdx.x, kc = blockIdx.y;
  int lane = threadIdx.x;
  int ml = lane & 15, q = lane >> 4;
  int row = mt * 16 + ml; if (row > N_ITEM - 1) row = N_ITEM - 1;
  size_t k0 = (size_t)kc * 256 + q * 8;
  const bh8* Ah = (const bh8*)(pool2h + (size_t)row * 8192 + k0);
  const bh8* Al = (const bh8*)(pool2l + (size_t)row * 8192 + k0);
  const bh8* Bh[4], * Bl[4];
#pragma unroll
  for (int nb = 0; nb < 4; ++nb) {
    Bh[nb] = (const bh8*)(whi + (size_t)(nb * 16 + ml) * 8192 + k0);
    Bl[nb] = (const bh8*)(wlo + (size_t)(nb * 16 + ml) * 8192 + k0);
  }
  f32x4 acc[4];
#pragma unroll
  for (int nb = 0; nb < 4; ++nb) acc[nb] = (f32x4){0.f, 0.f, 0.f, 0.f};
#pragma unroll
  for (int st = 0; st < 8; ++st) {
    bh8 ah = Ah[st * 4], al = Al[st * 4];
#pragma unroll
    for (int nb = 0; nb < 4; ++nb) {
      bh8 bhv = Bh[nb][st * 4], blv = Bl[nb][st * 4];
      acc[nb] = __builtin_amdgcn_mfma_f32_16x16x32_bf16(ah, bhv, acc[nb], 0, 0, 0);
      acc[nb] = __builtin_amdgcn_mfma_f32_16x16x32_bf16(ah, blv, acc[nb], 0, 0, 0);
      acc[nb] = __builtin_amdgcn_mfma_f32_16x16x32_bf16(al, bhv, acc[nb], 0, 0, 0);
    }
  }
#pragma unroll
  for (int r = 0; r < 4; ++r) {
    int mr = mt * 16 + q * 4 + r;
    if (mr < N_ITEM) {
      float* dst = xfc + (size_t)mr * 64 + ml;
#pragma unroll
      for (int nb = 0; nb < 4; ++nb) atomicAdd(dst + nb * 16, acc[nb][r]);
    }
  }
}

// ---------------- per-group, per-column batch norm (ddof=1) ----------------
__global__ __launch_bounds__(256) void k_norm(
    const float* __restrict__ xfc, float* __restrict__ item) {
  __shared__ float red[256];
  int grp = blockIdx.x >> 6;
  int o = blockIdx.x & 63;
  int base = grp ? N_CELL : 0;
  int N = grp ? N_DRUG : N_CELL;
  int tid = threadIdx.x;
  float s = 0.f;
  for (int i = tid; i < N; i += 256) s += xfc[(size_t)(base + i) * 64 + o];
  red[tid] = s; __syncthreads();
  for (int w = 128; w > 0; w >>= 1) { if (tid < w) red[tid] += red[tid + w]; __syncthreads(); }
  float mean = red[0] / (float)N;
  __syncthreads();
  float sq = 0.f;
  for (int i = tid; i < N; i += 256) {
    float d = xfc[(size_t)(base + i) * 64 + o] - mean;
    sq += d * d;
  }
  red[tid] = sq; __syncthreads();
  for (int w = 128; w > 0; w >>= 1) { if (tid < w) red[tid] += red[tid + w]; __syncthreads(); }
  float inv_std = 1.f / sqrtf(red[0] / (float)(N - 1));
  for (int i = tid; i < N; i += 256)
    item[(size_t)(base + i) * 64 + o] = (xfc[(size_t)(base + i) * 64 + o] - mean) * inv_std;
}

// ---------------- interact (2-hop attention) + agg GEMV + cell V precompute ----------------
__global__ __launch_bounds__(256) void k_interact(
    const int* __restrict__ cell_nbr, const int* __restrict__ drug_nbr,
    const float* __restrict__ protein, const float* __restrict__ item,
    const float* __restrict__ agg_w, const float* __restrict__ agg_b,
    const float* __restrict__ comb_w, float* __restrict__ emb,
    float* __restrict__ V) {
  __shared__ float pb[128 * 65];
  __shared__ float item_s[64];
  __shared__ float sc[128];
  __shared__ float hop_out[128];
  __shared__ float red[256];
  __shared__ float emb_f[64];
  int n = blockIdx.x;
  int tid = threadIdx.x;
  const int* nbr = (n < N_CELL) ? (cell_nbr + (size_t)n * 256)
                                : (drug_nbr + (size_t)(n - N_CELL) * 256);
  if (tid < 64) item_s[tid] = item[(size_t)n * 64 + tid];
  __syncthreads();
  for (int h = 0; h < 2; ++h) {
    for (int e = tid; e < 8192; e += 256) {
      int k = e >> 6, d = e & 63;
      int idx = nbr[h * 128 + k];
      pb[k * 65 + d] = protein[(size_t)idx * 64 + d];
    }
    __syncthreads();
    {
      int k = tid >> 1, halfd = tid & 1;
      int d0 = halfd * 32;
      float p = 0.f;
#pragma unroll
      for (int d = 0; d < 32; ++d) p += item_s[d0 + d] * pb[k * 65 + d0 + d];
      p += __shfl_xor(p, 1);
      if (halfd == 0) sc[k] = p;
    }
    __syncthreads();
    if (tid < 64) {
      float a = sc[tid], b = sc[tid + 64];
      float m = fmaxf(a, b);
#pragma unroll
      for (int off = 32; off > 0; off >>= 1) m = fmaxf(m, __shfl_xor(m, off));
      float e0 = __expf(a - m), e1 = __expf(b - m);
      float s = e0 + e1;
#pragma unroll
      for (int off = 32; off > 0; off >>= 1) s += __shfl_xor(s, off);
      float inv = 1.f / s;
      sc[tid] = e0 * inv; sc[tid + 64] = e1 * inv;
    }
    __syncthreads();
    {
      int d = tid & 63, kq = tid >> 6;
      float p = 0.f;
#pragma unroll
      for (int k = 0; k < 32; ++k) {
        int kk = kq * 32 + k;
        p += sc[kk] * pb[kk * 65 + d];
      }
      red[tid] = p;
    }
    __syncthreads();
    if (tid < 64)
      hop_out[h * 64 + tid] = red[tid] + red[tid + 64] + red[tid + 128] + red[tid + 192];
    __syncthreads();
  }
  {
    int o = tid & 63, jq = tid >> 6;
    float p = 0.f;
#pragma unroll
    for (int j = 0; j < 32; ++j) {
      int jj = jq * 32 + j;
      p += hop_out[jj] * agg_w[(size_t)o * 128 + jj];
    }
    red[tid] = p;
  }
  __syncthreads();
  if (tid < 64) {
    float ev = red[tid] + red[tid + 64] + red[tid + 128] + red[tid + 192] + agg_b[tid];
    emb[(size_t)n * 64 + tid] = ev;
    emb_f[tid] = ev;
  }
  if (n < N_CELL) {  // fused k_cellv: V[n] = comb_w^T @ emb[n]
    __syncthreads();
    if (tid < 128) {
      float s = 0.f;
#pragma unroll
      for (int o = 0; o < 64; ++o) s += comb_w[(size_t)o * 128 + tid] * emb_f[o];
      V[(size_t)n * 128 + tid] = s;
    }
  }
}

// ---------------- fused scoring + node reg + finalize (completion counter) ----------------
__global__ __launch_bounds__(256) void k_scoreall(
    const int* __restrict__ data, const int* __restrict__ cell_nbr,
    const int* __restrict__ drug_nbr, const float* __restrict__ protein,
    const float* __restrict__ emb, const float* __restrict__ V,
    float* __restrict__ out, float* __restrict__ loss, unsigned* __restrict__ cnt) {
  __shared__ float red[256];
  int bx = blockIdx.x;
  int tid = threadIdx.x;
  if (bx < 1024) {
    // ---- scoring: 4 batch items per block ----
    int lane = tid & 63;
    int w = tid >> 6;
    int b = bx * 4 + w;
    int c = data[b * 3 + 0], d1 = data[b * 3 + 1], d2 = data[b * 3 + 2];
    float ce = emb[(size_t)c * 64 + lane];
    float e1 = emb[(size_t)(N_CELL + d1) * 64 + lane];
    float e2 = emb[(size_t)(N_CELL + d2) * 64 + lane];
    float v1 = V[(size_t)c * 128 + lane];
    float v2 = V[(size_t)c * 128 + 64 + lane];
    float th = e1 * v1 + e2 * v2;
    float tx = e1 * e2;
    float rg = ce * ce + e1 * e1 + e2 * e2;
#pragma unroll
    for (int off = 32; off > 0; off >>= 1) {
      th += __shfl_xor(th, off);
      tx += __shfl_xor(tx, off);
      rg += __shfl_xor(rg, off);
    }
    if (lane == 0) { out[b] = th - tx; red[w] = rg; }
    __syncthreads();
    if (tid == 0) atomicAdd(loss, 0.5f * (red[0] + red[1] + red[2] + red[3]));
  } else {
    // ---- node regularization: 6 gathered rows (batch items 0,1) ----
    int j = bx - 1024;
    int hop = j / 3, which = j % 3;
    int row = data[hop * 3 + which];
    const int* nbr = (which == 0) ? (cell_nbr + (size_t)row * 256)
                                  : (drug_nbr + (size_t)row * 256);
    float acc = 0.f;
    for (int e = tid; e < 16384; e += 256) {
      int k = e >> 6, d = e & 63;
      float v = protein[(size_t)nbr[k] * 64 + d];
      acc += v * v;
    }
    red[tid] = acc; __syncthreads();
    for (int w = 128; w > 0; w >>= 1) { if (tid < w) red[tid] += red[tid + w]; __syncthreads(); }
    if (tid == 0) atomicAdd(loss, 0.5f * red[0]);
  }
  // ---- finalize: last block to retire reads the fully-accumulated loss ----
  if (tid == 0) {
    __threadfence();
    unsigned old = atomicAdd(cnt, 1u);
    if (old == gridDim.x - 1) {
      float L = atomicAdd(loss, 0.f);  // device-coherent read
      out[BATCH] = L * (1e-6f / 4096.f);
    }
  }
}

extern "C" void kernel_launch(void* const* d_in, const int* in_sizes, int n_in,
                              void* d_out, int out_size, void* d_ws, size_t ws_size,
                              hipStream_t stream) {
  const int*   data      = (const int*)d_in[0];
  const int*   cell_nbr  = (const int*)d_in[1];
  const int*   drug_nbr  = (const int*)d_in[2];
  const float* protein   = (const float*)d_in[3];
  const float* cell_pre  = (const float*)d_in[4];
  const float* drug_pre  = (const float*)d_in[5];
  const float* w1        = (const float*)d_in[6];
  const float* b1        = (const float*)d_in[7];
  const float* w2        = (const float*)d_in[8];
  const float* b2        = (const float*)d_in[9];
  const float* out_w     = (const float*)d_in[10];
  const float* agg_w     = (const float*)d_in[12];
  const float* agg_b     = (const float*)d_in[13];
  const float* comb_w    = (const float*)d_in[14];
  float* out = (float*)d_out;
  char* base = (char*)d_ws;
  unsigned short* pool2h  = (unsigned short*)(base + POOL2H_B);
  unsigned short* pool2l  = (unsigned short*)(base + POOL2L_B);
  unsigned short* whi     = (unsigned short*)(base + WHI_B);
  unsigned short* wlo     = (unsigned short*)(base + WLO_B);
  float* xfc              = (float*)(base + XFC_B);
  float* item             = (float*)(base + ITEM_B);
  float* emb              = (float*)(base + EMB_B);
  float* V                = (float*)(base + V_B);
  float* loss             = (float*)(base + LOSS_B);
  unsigned* cnt           = (unsigned*)(base + CNT_B);

  k_conv12<<<dim3(4, 845), 256, 0, stream>>>(cell_pre, drug_pre, w1, b1, w2, b2, out_w,
                                             pool2h, pool2l, whi, wlo, xfc, loss, cnt);
  k_fc<<<dim3(53, 32), 64, 0, stream>>>(pool2h, pool2l, whi, wlo, xfc);
  k_norm<<<128, 256, 0, stream>>>(xfc, item);
  k_interact<<<840, 256, 0, stream>>>(cell_nbr, drug_nbr, protein, item, agg_w, agg_b,
                                      comb_w, emb, V);
  k_scoreall<<<1030, 256, 0, stream>>>(data, cell_nbr, drug_nbr, protein, emb, V, out, loss, cnt);
}

// Round 3
// 251.321 us; speedup vs baseline: 1.0075x; 1.0075x over previous
//
#include <hip/hip_runtime.h>
#include <hip/hip_bf16.h>
#include <math.h>

#define N_CELL 76
#define N_DRUG 764
#define N_ITEM 840
#define BATCH  4096

// ws layout (byte offsets)
#define POOL2H_B 0u
#define POOL2L_B 13762560u
#define WHI_B    27525120u
#define WLO_B    28573696u
#define XFC_B    29622272u
#define ITEM_B   29837312u
#define EMB_B    30052352u
#define V_B      30267392u
#define LOSS_B   30306304u
#define CNT_B    30306368u

typedef short bh8 __attribute__((ext_vector_type(8)));
typedef short bh4 __attribute__((ext_vector_type(4)));
typedef float f32x4 __attribute__((ext_vector_type(4)));

static __device__ inline unsigned short f2bf(float f) {
  union { float f; unsigned u; } v; v.f = f;
  unsigned r = v.u + 0x7FFFu + ((v.u >> 16) & 1u);  // RNE (no NaN inputs here)
  return (unsigned short)(r >> 16);
}
static __device__ inline float bf2f(unsigned short h) {
  union { unsigned u; float f; } v; v.u = ((unsigned)h) << 16;
  return v.f;
}
// lo residual via truncation (residual <= 2^-9|a|, trunc err <= 2^-17|a|)
static __device__ inline unsigned short f2bf_lo(float f, unsigned short h) {
  union { float f; unsigned u; } a; a.f = f - bf2f(h);
  return (unsigned short)(a.u >> 16);
}

union BH8U { bh8 v; struct { bh4 lo, hi; } s; };

// ---------------- fused conv1+pool1+conv2+pool2 (quarter blocks, 8 waves) ----------------
// Block = conv2-quarter (8 pool2 rows), 512 threads. LDS 39.7KB -> 4 blocks/CU
// x 8 waves = 32 waves/CU (100% slot cap). Blocks with blockIdx.y>=840 do the
// out_w cast + zeroing.
__global__ __launch_bounds__(512) void k_conv12(
    const float* __restrict__ cell_pre, const float* __restrict__ drug_pre,
    const float* __restrict__ w1, const float* __restrict__ b1,
    const float* __restrict__ w2, const float* __restrict__ b2,
    const float* __restrict__ out_w,
    unsigned short* __restrict__ pool2h, unsigned short* __restrict__ pool2l,
    unsigned short* __restrict__ whi, unsigned short* __restrict__ wlo,
    float* __restrict__ xfc, float* __restrict__ loss, unsigned* __restrict__ cnt) {
  __shared__ unsigned short slh[38 * 34 * 4];
  __shared__ unsigned short sll[38 * 34 * 4];
  __shared__ unsigned short p1h[18 * 66 * 4];
  __shared__ unsigned short p1l[18 * 66 * 4];
  int n = blockIdx.y;
  int tid = threadIdx.x;
  if (n >= 840) {
    // ---- cast/zero blocks: 5 y-rows x 4 = 20 blocks, 10240 threads ----
    int cb = (n - 840) * 4 + blockIdx.x;
    int gid = cb * 512 + tid;  // 0..10239
    if (gid == 0) { *loss = 0.f; *cnt = 0u; }
    for (int i = gid; i < 13440; i += 10240)  // zero xfc (840*64 f32)
      ((float4*)xfc)[i] = make_float4(0.f, 0.f, 0.f, 0.f);
    for (int i = gid; i < 131072; i += 10240) {  // split-cast out_w
      float4 v = ((const float4*)out_w)[i];
      ushort4 h, l;
      h.x = f2bf(v.x); l.x = f2bf(v.x - bf2f(h.x));
      h.y = f2bf(v.y); l.y = f2bf(v.y - bf2f(h.y));
      h.z = f2bf(v.z); l.z = f2bf(v.z - bf2f(h.z));
      h.w = f2bf(v.w); l.w = f2bf(v.w - bf2f(h.w));
      ((ushort4*)whi)[i] = h;
      ((ushort4*)wlo)[i] = l;
    }
    return;
  }
  int qt = blockIdx.x;  // conv2-quarter 0..3
  // ---- stage input rows iy = 32*qt - 3 + lr, lr = 0..37 ----
  const float4* src = (const float4*)((n < N_CELL) ? (cell_pre + (size_t)n * 16384)
                                                   : (drug_pre + (size_t)(n - N_CELL) * 16384));
  for (int i = tid; i < 38 * 32; i += 512) {
    int lr = i >> 5, g = i & 31;
    int iy = qt * 32 - 3 + lr;
    float4 v = make_float4(0.f, 0.f, 0.f, 0.f);
    if (iy >= 0 && iy < 128) v = src[iy * 32 + g];
    ushort4 h, l;
    h.x = f2bf(v.x); l.x = f2bf_lo(v.x, h.x);
    h.y = f2bf(v.y); l.y = f2bf_lo(v.y, h.y);
    h.z = f2bf(v.z); l.z = f2bf_lo(v.z, h.z);
    h.w = f2bf(v.w); l.w = f2bf_lo(v.w, h.w);
    ((ushort4*)slh)[lr * 34 + g + 1] = h;
    ((ushort4*)sll)[lr * 34 + g + 1] = l;
  }
  if (tid < 76) {  // input x-pad
    int lr = tid >> 1, g = (tid & 1) ? 33 : 0;
    ushort4 z = make_ushort4(0, 0, 0, 0);
    ((ushort4*)slh)[lr * 34 + g] = z;
    ((ushort4*)sll)[lr * 34 + g] = z;
  }
  if (tid < 36) {  // pool1-tile x-pad (cols 0 and 65)
    int r = tid >> 1, c = (tid & 1) ? 65 : 0;
    ushort4 z = make_ushort4(0, 0, 0, 0);
    ((ushort4*)p1h)[r * 66 + c] = z;
    ((ushort4*)p1l)[r * 66 + c] = z;
  }
  int wv = tid >> 6;   // 0..7
  int lane = tid & 63;
  int ml = lane & 15, q = lane >> 4;

  // ---- conv1 B fragments (lane = col ml; k = q*8+j; r=q, w=j) ----
  int oc = ml & 3, yv1 = (ml >> 2) & 1, hi = ml >> 3;
  float bb = b1[oc];
  bh8 BhE, BlE, BhO, BlO;
  {
    int kr = q - yv1;
    bool krok = (kr >= 0 && kr <= 2);
#pragma unroll
    for (int j = 0; j < 8; ++j) {
      float ve = 0.f, vo = 0.f;
      if (krok) {
        int kse = j - 3 - 2 * hi;   // even phases 0/2
        int kso = j - 2 * hi;       // odd  phases 1/3
        if (kse >= 0 && kse <= 2) ve = w1[oc * 9 + kr * 3 + kse];
        if (kso >= 0 && kso <= 2) vo = w1[oc * 9 + kr * 3 + kso];
      }
      unsigned short he = f2bf(ve), ho = f2bf(vo);
      BhE[j] = (short)he; BlE[j] = (short)f2bf_lo(ve, he);
      BhO[j] = (short)ho; BlO[j] = (short)f2bf_lo(vo, ho);
    }
  }
  // ---- conv2 B fragments ----
  int oc_b = ml & 7, yv2 = ml >> 3;
  bh8 Bh2[2], Bl2[2];
#pragma unroll
  for (int ch = 0; ch < 2; ++ch) {
#pragma unroll
    for (int j = 0; j < 8; ++j) {
      int kg = ch * 32 + q * 8 + j;
      float v = 0.f;
      if (kg < 48) {
        int r = kg / 12, rem = kg - r * 12;
        int ks = rem >> 2, ic = rem & 3;
        int kr = r - yv2;
        if (kr >= 0 && kr <= 2) v = w2[(oc_b * 4 + ic) * 9 + kr * 3 + ks];
      } else if (kg == 48) {
        v = b2[oc_b];
      }
      unsigned short h = f2bf(v);
      Bh2[ch][j] = (short)h;
      Bl2[ch][j] = (short)f2bf_lo(v, h);
    }
  }
  // conv2 A-offsets
  int c0 = 2 * q, c1 = 2 * q + 1;
  int c2 = 8 + 2 * q, c3 = 9 + 2 * q;
  if (c2 > 11) { c2 = 8; c3 = 9; }
  int r0 = (c0 * 86) >> 8, s0 = c0 - 3 * r0;
  int r1 = (c1 * 86) >> 8, s1 = c1 - 3 * r1;
  int r2 = (c2 * 86) >> 8, s2 = c2 - 3 * r2;
  int r3 = (c3 * 86) >> 8, s3 = c3 - 3 * r3;
  int x2 = (wv & 3) << 4;
  int off0 = r0 * 66 + x2 + ml + s0;
  int off1 = r1 * 66 + x2 + ml + s1;
  int off2 = r2 * 66 + x2 + ml + s2;
  int off3 = r3 * 66 + x2 + ml + s3;
  __syncthreads();

  // ---- conv1 phase: wave = (wv&1) x-half (32 px) x {5,5,4,4} tile rows ----
  int x0 = (wv & 1) * 16;
  int g1 = wv >> 1;  // 0..3
  int rbase = (g1 < 2) ? g1 * 5 : 10 + (g1 - 2) * 4;
  int rcnt  = (g1 < 2) ? 5 : 4;
  int Lb = x0 + ml;
  const bh4* lh4 = (const bh4*)slh;
  const bh4* ll4 = (const bh4*)sll;
#pragma unroll 1
  for (int ii = 0; ii < rcnt; ++ii) {
    int i = rbase + ii;          // pool1-tile row 0..17
    int base = (2 * i + q) * 34 + Lb;
    bh4 g0h = lh4[base], g1h = lh4[base + 1], g2h = lh4[base + 2];
    bh4 g0l = ll4[base], g1l = ll4[base + 1], g2l = ll4[base + 2];
    BH8U aeh, ael, aoh, aol;
    aeh.s.lo = g0h; aeh.s.hi = g1h;
    ael.s.lo = g0l; ael.s.hi = g1l;
    aoh.s.lo = g1h; aoh.s.hi = g2h;
    aol.s.lo = g1l; aol.s.hi = g2l;
    f32x4 de = {0.f, 0.f, 0.f, 0.f}, dd = de;
    de = __builtin_amdgcn_mfma_f32_16x16x32_bf16(aeh.v, BhE, de, 0, 0, 0);
    de = __builtin_amdgcn_mfma_f32_16x16x32_bf16(aeh.v, BlE, de, 0, 0, 0);
    de = __builtin_amdgcn_mfma_f32_16x16x32_bf16(ael.v, BhE, de, 0, 0, 0);
    dd = __builtin_amdgcn_mfma_f32_16x16x32_bf16(aoh.v, BhO, dd, 0, 0, 0);
    dd = __builtin_amdgcn_mfma_f32_16x16x32_bf16(aoh.v, BlO, dd, 0, 0, 0);
    dd = __builtin_amdgcn_mfma_f32_16x16x32_bf16(aol.v, BhO, dd, 0, 0, 0);
    int pr = qt * 16 - 1 + i;    // global pool1 row (halo rows may be out of range)
    bool inr = (pr >= 0 && pr < 64);
#pragma unroll
    for (int r = 0; r < 4; ++r) {
      float t = fmaxf(de[r], dd[r]);        // x-pool
      float t2 = __shfl_xor(t, 4);          // y-pool partner
      if (yv1 == 0) {
        float val = fmaxf(fmaxf(t, t2) + bb, 0.f);
        if (!inr) val = 0.f;                // conv2 zero-padding rows
        unsigned short h = f2bf(val);
        unsigned short l = f2bf_lo(val, h);
        int px = 2 * (x0 + q * 4 + r) + hi;
        int idx = (i * 66 + px + 1) * 4 + oc;
        p1h[idx] = h; p1l[idx] = l;
      }
    }
  }
  __syncthreads();

  // ---- conv2 phase: wave = (wv&3) x-strip x 4 rp rows ----
  int rp0 = (wv >> 2) * 4;
  const bh4* ph4 = (const bh4*)p1h;
  const bh4* pl4 = (const bh4*)p1l;
#pragma unroll 1
  for (int rr = 0; rr < 4; ++rr) {
    int rp = rp0 + rr;
    int base2 = 2 * rp * 66;
    BH8U ah0, al0, ah1, al1;
    ah0.s.lo = ph4[base2 + off0]; ah0.s.hi = ph4[base2 + off1];
    al0.s.lo = pl4[base2 + off0]; al0.s.hi = pl4[base2 + off1];
    if (q < 2) {
      ah1.s.lo = ph4[base2 + off2]; ah1.s.hi = ph4[base2 + off3];
      al1.s.lo = pl4[base2 + off2]; al1.s.hi = pl4[base2 + off3];
    } else {
#pragma unroll
      for (int j = 0; j < 8; ++j) { ah1.v[j] = 0; al1.v[j] = 0; }
      if (q == 2) ah1.v[0] = (short)0x3F80;  // bf16 1.0 -> bias row k=48
    }
    f32x4 accA = {0.f, 0.f, 0.f, 0.f}, accB = accA;
    accA = __builtin_amdgcn_mfma_f32_16x16x32_bf16(ah0.v, Bh2[0], accA, 0, 0, 0);
    accA = __builtin_amdgcn_mfma_f32_16x16x32_bf16(ah0.v, Bl2[0], accA, 0, 0, 0);
    accA = __builtin_amdgcn_mfma_f32_16x16x32_bf16(al0.v, Bh2[0], accA, 0, 0, 0);
    accB = __builtin_amdgcn_mfma_f32_16x16x32_bf16(ah1.v, Bh2[1], accB, 0, 0, 0);
    accB = __builtin_amdgcn_mfma_f32_16x16x32_bf16(ah1.v, Bl2[1], accB, 0, 0, 0);
    accB = __builtin_amdgcn_mfma_f32_16x16x32_bf16(al1.v, Bh2[1], accB, 0, 0, 0);
    float d0 = accA[0] + accB[0], d1 = accA[1] + accB[1];
    float d2 = accA[2] + accB[2], d3 = accA[3] + accB[3];
    float m0 = fmaxf(d0, d1), m1 = fmaxf(d2, d3);
    float o0 = __shfl_xor(m0, 8), o1 = __shfl_xor(m1, 8);
    m0 = fmaxf(fmaxf(m0, o0), 0.f);
    m1 = fmaxf(fmaxf(m1, o1), 0.f);
    if (yv2 == 0) {
      unsigned short h0 = f2bf(m0), h1 = f2bf(m1);
      unsigned short l0 = f2bf(m0 - bf2f(h0)), l1 = f2bf(m1 - bf2f(h1));
      int PR = qt * 8 + rp;
      unsigned ui = (unsigned)n * 4096u + (unsigned)oc_b * 512u +
                    (unsigned)PR * 16u + (unsigned)(x2 >> 2) + (unsigned)q;
      ((unsigned*)pool2h)[ui] = (unsigned)h0 | ((unsigned)h1 << 16);
      ((unsigned*)pool2l)[ui] = (unsigned)l0 | ((unsigned)l1 << 16);
    }
  }
}

// ---------------- FC: split-bf16 MFMA GEMM, M=840 N=64, K chunks of 256 ----------------
__global__ __launch_bounds__(64) void k_fc(
    const unsigned short* __restrict__ pool2h, const unsigned short* __restrict__ pool2l,
    const unsigned short* __restrict__ whi, const unsigned short* __restrict__ wlo,
    float* __restrict__ xfc) {
  int mt = blockIdx.x, kc = blockIdx.y;
  int lane = threadIdx.x;
  int ml = lane & 15, q = lane >> 4;
  int row = mt * 16 + ml; if (row > N_ITEM - 1) row = N_ITEM - 1;
  size_t k0 = (size_t)kc * 256 + q * 8;
  const bh8* Ah = (const bh8*)(pool2h + (size_t)row * 8192 + k0);
  const bh8* Al = (const bh8*)(pool2l + (size_t)row * 8192 + k0);
  const bh8* Bh[4], * Bl[4];
#pragma unroll
  for (int nb = 0; nb < 4; ++nb) {
    Bh[nb] = (const bh8*)(whi + (size_t)(nb * 16 + ml) * 8192 + k0);
    Bl[nb] = (const bh8*)(wlo + (size_t)(nb * 16 + ml) * 8192 + k0);
  }
  f32x4 acc[4];
#pragma unroll
  for (int nb = 0; nb < 4; ++nb) acc[nb] = (f32x4){0.f, 0.f, 0.f, 0.f};
#pragma unroll
  for (int st = 0; st < 8; ++st) {
    bh8 ah = Ah[st * 4], al = Al[st * 4];
#pragma unroll
    for (int nb = 0; nb < 4; ++nb) {
      bh8 bhv = Bh[nb][st * 4], blv = Bl[nb][st * 4];
      acc[nb] = __builtin_amdgcn_mfma_f32_16x16x32_bf16(ah, bhv, acc[nb], 0, 0, 0);
      acc[nb] = __builtin_amdgcn_mfma_f32_16x16x32_bf16(ah, blv, acc[nb], 0, 0, 0);
      acc[nb] = __builtin_amdgcn_mfma_f32_16x16x32_bf16(al, bhv, acc[nb], 0, 0, 0);
    }
  }
#pragma unroll
  for (int r = 0; r < 4; ++r) {
    int mr = mt * 16 + q * 4 + r;
    if (mr < N_ITEM) {
      float* dst = xfc + (size_t)mr * 64 + ml;
#pragma unroll
      for (int nb = 0; nb < 4; ++nb) atomicAdd(dst + nb * 16, acc[nb][r]);
    }
  }
}

// ---------------- per-group, per-column batch norm (ddof=1) ----------------
__global__ __launch_bounds__(256) void k_norm(
    const float* __restrict__ xfc, float* __restrict__ item) {
  __shared__ float red[256];
  int grp = blockIdx.x >> 6;
  int o = blockIdx.x & 63;
  int base = grp ? N_CELL : 0;
  int N = grp ? N_DRUG : N_CELL;
  int tid = threadIdx.x;
  float s = 0.f;
  for (int i = tid; i < N; i += 256) s += xfc[(size_t)(base + i) * 64 + o];
  red[tid] = s; __syncthreads();
  for (int w = 128; w > 0; w >>= 1) { if (tid < w) red[tid] += red[tid + w]; __syncthreads(); }
  float mean = red[0] / (float)N;
  __syncthreads();
  float sq = 0.f;
  for (int i = tid; i < N; i += 256) {
    float d = xfc[(size_t)(base + i) * 64 + o] - mean;
    sq += d * d;
  }
  red[tid] = sq; __syncthreads();
  for (int w = 128; w > 0; w >>= 1) { if (tid < w) red[tid] += red[tid + w]; __syncthreads(); }
  float inv_std = 1.f / sqrtf(red[0] / (float)(N - 1));
  for (int i = tid; i < N; i += 256)
    item[(size_t)(base + i) * 64 + o] = (xfc[(size_t)(base + i) * 64 + o] - mean) * inv_std;
}

// ---------------- interact: both hops concurrent (512 thr) + agg GEMV + cell V ----------------
__global__ __launch_bounds__(512) void k_interact(
    const int* __restrict__ cell_nbr, const int* __restrict__ drug_nbr,
    const float* __restrict__ protein, const float* __restrict__ item,
    const float* __restrict__ agg_w, const float* __restrict__ agg_b,
    const float* __restrict__ comb_w, float* __restrict__ emb,
    float* __restrict__ V) {
  __shared__ float pb[2][128 * 65];
  __shared__ float item_s[64];
  __shared__ float sc[2][128];
  __shared__ float hop_out[128];
  __shared__ float red[512];
  __shared__ float emb_f[64];
  int n = blockIdx.x;
  int tid = threadIdx.x;
  int ht = tid >> 8;      // hop 0/1
  int t = tid & 255;      // thread within hop
  const int* nbr = (n < N_CELL) ? (cell_nbr + (size_t)n * 256)
                                : (drug_nbr + (size_t)(n - N_CELL) * 256);
  if (tid < 64) item_s[tid] = item[(size_t)n * 64 + tid];
  __syncthreads();
  // stage this hop's 128 gathered protein rows
  for (int e = t; e < 8192; e += 256) {
    int k = e >> 6, d = e & 63;
    int idx = nbr[ht * 128 + k];
    pb[ht][k * 65 + d] = protein[(size_t)idx * 64 + d];
  }
  __syncthreads();
  {  // scores: 2 threads per k
    int k = t >> 1, halfd = t & 1;
    int d0 = halfd * 32;
    float p = 0.f;
#pragma unroll
    for (int d = 0; d < 32; ++d) p += item_s[d0 + d] * pb[ht][k * 65 + d0 + d];
    p += __shfl_xor(p, 1);
    if (halfd == 0) sc[ht][k] = p;
  }
  __syncthreads();
  if (t < 64) {  // softmax over 128 (waves 0 and 4)
    float a = sc[ht][t], b = sc[ht][t + 64];
    float m = fmaxf(a, b);
#pragma unroll
    for (int off = 32; off > 0; off >>= 1) m = fmaxf(m, __shfl_xor(m, off));
    float e0 = __expf(a - m), e1 = __expf(b - m);
    float s = e0 + e1;
#pragma unroll
    for (int off = 32; off > 0; off >>= 1) s += __shfl_xor(s, off);
    float inv = 1.f / s;
    sc[ht][t] = e0 * inv; sc[ht][t + 64] = e1 * inv;
  }
  __syncthreads();
  {  // PV: 4 k-chunks x 64 d
    int d = t & 63, kq = t >> 6;
    float p = 0.f;
#pragma unroll
    for (int k = 0; k < 32; ++k) {
      int kk = kq * 32 + k;
      p += sc[ht][kk] * pb[ht][kk * 65 + d];
    }
    red[tid] = p;
  }
  __syncthreads();
  if (t < 64)
    hop_out[ht * 64 + t] = red[ht * 256 + t] + red[ht * 256 + t + 64] +
                           red[ht * 256 + t + 128] + red[ht * 256 + t + 192];
  __syncthreads();
  {  // agg GEMV: 8 j-chunks of 16
    int o = tid & 63, jq = tid >> 6;
    float p = 0.f;
#pragma unroll
    for (int j = 0; j < 16; ++j) {
      int jj = jq * 16 + j;
      p += hop_out[jj] * agg_w[(size_t)o * 128 + jj];
    }
    red[tid] = p;
  }
  __syncthreads();
  if (tid < 64) {
    float ev = red[tid] + red[tid + 64] + red[tid + 128] + red[tid + 192] +
               red[tid + 256] + red[tid + 320] + red[tid + 384] + red[tid + 448] +
               agg_b[tid];
    emb[(size_t)n * 64 + tid] = ev;
    emb_f[tid] = ev;
  }
  if (n < N_CELL) {  // fused k_cellv: V[n] = comb_w^T @ emb[n]
    __syncthreads();
    if (tid < 128) {
      float s = 0.f;
#pragma unroll
      for (int o = 0; o < 64; ++o) s += comb_w[(size_t)o * 128 + tid] * emb_f[o];
      V[(size_t)n * 128 + tid] = s;
    }
  }
}

// ---------------- fused scoring + node reg + finalize (completion counter) ----------------
__global__ __launch_bounds__(256) void k_scoreall(
    const int* __restrict__ data, const int* __restrict__ cell_nbr,
    const int* __restrict__ drug_nbr, const float* __restrict__ protein,
    const float* __restrict__ emb, const float* __restrict__ V,
    float* __restrict__ out, float* __restrict__ loss, unsigned* __restrict__ cnt) {
  __shared__ float red[256];
  int bx = blockIdx.x;
  int tid = threadIdx.x;
  if (bx < 1024) {
    // ---- scoring: 4 batch items per block ----
    int lane = tid & 63;
    int w = tid >> 6;
    int b = bx * 4 + w;
    int c = data[b * 3 + 0], d1 = data[b * 3 + 1], d2 = data[b * 3 + 2];
    float ce = emb[(size_t)c * 64 + lane];
    float e1 = emb[(size_t)(N_CELL + d1) * 64 + lane];
    float e2 = emb[(size_t)(N_CELL + d2) * 64 + lane];
    float v1 = V[(size_t)c * 128 + lane];
    float v2 = V[(size_t)c * 128 + 64 + lane];
    float th = e1 * v1 + e2 * v2;
    float tx = e1 * e2;
    float rg = ce * ce + e1 * e1 + e2 * e2;
#pragma unroll
    for (int off = 32; off > 0; off >>= 1) {
      th += __shfl_xor(th, off);
      tx += __shfl_xor(tx, off);
      rg += __shfl_xor(rg, off);
    }
    if (lane == 0) { out[b] = th - tx; red[w] = rg; }
    __syncthreads();
    if (tid == 0) atomicAdd(loss, 0.5f * (red[0] + red[1] + red[2] + red[3]));
  } else {
    // ---- node regularization: 6 gathered rows (batch items 0,1) ----
    int j = bx - 1024;
    int hop = j / 3, which = j % 3;
    int row = data[hop * 3 + which];
    const int* nbr = (which == 0) ? (cell_nbr + (size_t)row * 256)
                                  : (drug_nbr + (size_t)row * 256);
    float acc = 0.f;
    for (int e = tid; e < 16384; e += 256) {
      int k = e >> 6, d = e & 63;
      float v = protein[(size_t)nbr[k] * 64 + d];
      acc += v * v;
    }
    red[tid] = acc; __syncthreads();
    for (int w = 128; w > 0; w >>= 1) { if (tid < w) red[tid] += red[tid + w]; __syncthreads(); }
    if (tid == 0) atomicAdd(loss, 0.5f * red[0]);
  }
  // ---- finalize: last block to retire reads the fully-accumulated loss ----
  if (tid == 0) {
    __threadfence();
    unsigned old = atomicAdd(cnt, 1u);
    if (old == gridDim.x - 1) {
      float L = atomicAdd(loss, 0.f);  // device-coherent read
      out[BATCH] = L * (1e-6f / 4096.f);
    }
  }
}

extern "C" void kernel_launch(void* const* d_in, const int* in_sizes, int n_in,
                              void* d_out, int out_size, void* d_ws, size_t ws_size,
                              hipStream_t stream) {
  const int*   data      = (const int*)d_in[0];
  const int*   cell_nbr  = (const int*)d_in[1];
  const int*   drug_nbr  = (const int*)d_in[2];
  const float* protein   = (const float*)d_in[3];
  const float* cell_pre  = (const float*)d_in[4];
  const float* drug_pre  = (const float*)d_in[5];
  const float* w1        = (const float*)d_in[6];
  const float* b1        = (const float*)d_in[7];
  const float* w2        = (const float*)d_in[8];
  const float* b2        = (const float*)d_in[9];
  const float* out_w     = (const float*)d_in[10];
  const float* agg_w     = (const float*)d_in[12];
  const float* agg_b     = (const float*)d_in[13];
  const float* comb_w    = (const float*)d_in[14];
  float* out = (float*)d_out;
  char* base = (char*)d_ws;
  unsigned short* pool2h  = (unsigned short*)(base + POOL2H_B);
  unsigned short* pool2l  = (unsigned short*)(base + POOL2L_B);
  unsigned short* whi     = (unsigned short*)(base + WHI_B);
  unsigned short* wlo     = (unsigned short*)(base + WLO_B);
  float* xfc              = (float*)(base + XFC_B);
  float* item             = (float*)(base + ITEM_B);
  float* emb              = (float*)(base + EMB_B);
  float* V                = (float*)(base + V_B);
  float* loss             = (float*)(base + LOSS_B);
  unsigned* cnt           = (unsigned*)(base + CNT_B);

  k_conv12<<<dim3(4, 845), 512, 0, stream>>>(cell_pre, drug_pre, w1, b1, w2, b2, out_w,
                                             pool2h, pool2l, whi, wlo, xfc, loss, cnt);
  k_fc<<<dim3(53, 32), 64, 0, stream>>>(pool2h, pool2l, whi, wlo, xfc);
  k_norm<<<128, 256, 0, stream>>>(xfc, item);
  k_interact<<<840, 512, 0, stream>>>(cell_nbr, drug_nbr, protein, item, agg_w, agg_b,
                                      comb_w, emb, V);
  k_scoreall<<<1030, 256, 0, stream>>>(data, cell_nbr, drug_nbr, protein, emb, V, out, loss, cnt);
}

// Round 4
// 237.537 us; speedup vs baseline: 1.0659x; 1.0580x over previous
//
#include <hip/hip_runtime.h>
#include <hip/hip_bf16.h>
#include <math.h>

#define N_CELL 76
#define N_DRUG 764
#define N_ITEM 840
#define BATCH  4096

// ws layout (byte offsets)
#define POOL2H_B 0u
#define POOL2L_B 13762560u
#define WHI_B    27525120u
#define WLO_B    28573696u
#define XFC_B    29622272u
#define ITEM_B   29837312u
#define EMB_B    30052352u
#define V_B      30267392u
#define LOSS_B   30306304u
#define CNT_B    30306368u
#define FRAG_B   30306432u   // 8 sets x 64 lanes x 16B = 8KB

typedef short bh8 __attribute__((ext_vector_type(8)));
typedef short bh4 __attribute__((ext_vector_type(4)));
typedef float f32x4 __attribute__((ext_vector_type(4)));

static __device__ inline unsigned short f2bf(float f) {
  union { float f; unsigned u; } v; v.f = f;
  unsigned r = v.u + 0x7FFFu + ((v.u >> 16) & 1u);  // RNE (no NaN inputs here)
  return (unsigned short)(r >> 16);
}
static __device__ inline float bf2f(unsigned short h) {
  union { unsigned u; float f; } v; v.u = ((unsigned)h) << 16;
  return v.f;
}
// lo residual via truncation (residual <= 2^-9|a|, trunc err <= 2^-17|a|)
static __device__ inline unsigned short f2bf_lo(float f, unsigned short h) {
  union { float f; unsigned u; } a; a.f = f - bf2f(h);
  return (unsigned short)(a.u >> 16);
}
// hw packed RNE f32->bf16 (gfx950): dst = [bf16(b) : bf16(a)]
static __device__ inline unsigned cvtpk(float a, float b) {
  unsigned r;
  asm("v_cvt_pk_bf16_f32 %0, %1, %2" : "=v"(r) : "v"(a), "v"(b));
  return r;
}
static __device__ inline float fromu(unsigned u) {
  union { unsigned u; float f; } v; v.u = u; return v.f;
}
static __device__ inline unsigned asu(float f) {
  union { float f; unsigned u; } v; v.f = f; return v.u;
}

union BH8U { bh8 v; struct { bh4 lo, hi; } s; };

// ---------------- precompute per-lane weight fragments (once) ----------------
__global__ __launch_bounds__(64) void k_prep(
    const float* __restrict__ w1, const float* __restrict__ w2,
    const float* __restrict__ b2, bh8* __restrict__ ftab,
    float* __restrict__ loss, unsigned* __restrict__ cnt) {
  int lane = threadIdx.x & 63;
  int ml = lane & 15, q = lane >> 4;
  int oc = ml & 3, yv1 = (ml >> 2) & 1, hi = ml >> 3;
  bh8 BhE, BlE, BhO, BlO;
  {
    int kr = q - yv1;
    bool krok = (kr >= 0 && kr <= 2);
#pragma unroll
    for (int j = 0; j < 8; ++j) {
      float ve = 0.f, vo = 0.f;
      if (krok) {
        int kse = j - 3 - 2 * hi;   // even phases 0/2
        int kso = j - 2 * hi;       // odd  phases 1/3
        if (kse >= 0 && kse <= 2) ve = w1[oc * 9 + kr * 3 + kse];
        if (kso >= 0 && kso <= 2) vo = w1[oc * 9 + kr * 3 + kso];
      }
      unsigned short he = f2bf(ve), ho = f2bf(vo);
      BhE[j] = (short)he; BlE[j] = (short)f2bf_lo(ve, he);
      BhO[j] = (short)ho; BlO[j] = (short)f2bf_lo(vo, ho);
    }
  }
  int oc_b = ml & 7, yv2 = ml >> 3;
  bh8 Bh2[2], Bl2[2];
#pragma unroll
  for (int ch = 0; ch < 2; ++ch) {
#pragma unroll
    for (int j = 0; j < 8; ++j) {
      int kg = ch * 32 + q * 8 + j;
      float v = 0.f;
      if (kg < 48) {
        int r = kg / 12, rem = kg - r * 12;
        int ks = rem >> 2, ic = rem & 3;
        int kr = r - yv2;
        if (kr >= 0 && kr <= 2) v = w2[(oc_b * 4 + ic) * 9 + kr * 3 + ks];
      } else if (kg == 48) {
        v = b2[oc_b];
      }
      unsigned short h = f2bf(v);
      Bh2[ch][j] = (short)h;
      Bl2[ch][j] = (short)f2bf_lo(v, h);
    }
  }
  ftab[lane] = BhE;          ftab[64 + lane] = BlE;
  ftab[128 + lane] = BhO;    ftab[192 + lane] = BlO;
  ftab[256 + lane] = Bh2[0]; ftab[320 + lane] = Bl2[0];
  ftab[384 + lane] = Bh2[1]; ftab[448 + lane] = Bl2[1];
  if (lane == 0) { *loss = 0.f; *cnt = 0u; }
}

// ---------------- fused conv1+pool1+conv2+pool2 (quarter blocks, 8 waves) ----------------
__global__ __launch_bounds__(512) void k_conv12(
    const float* __restrict__ cell_pre, const float* __restrict__ drug_pre,
    const float* __restrict__ b1, const float* __restrict__ out_w,
    const bh8* __restrict__ ftab,
    unsigned short* __restrict__ pool2h, unsigned short* __restrict__ pool2l,
    unsigned short* __restrict__ whi, unsigned short* __restrict__ wlo,
    float* __restrict__ xfc) {
  __shared__ unsigned short slh[38 * 34 * 4];
  __shared__ unsigned short sll[38 * 34 * 4];
  __shared__ unsigned short p1h[18 * 66 * 4];
  __shared__ unsigned short p1l[18 * 66 * 4];
  int n = blockIdx.y;
  int tid = threadIdx.x;
  if (n >= 840) {
    // ---- cast/zero blocks: 5 y-rows x 4 = 20 blocks, 10240 threads ----
    int cb = (n - 840) * 4 + blockIdx.x;
    int gid = cb * 512 + tid;  // 0..10239
    for (int i = gid; i < 13440; i += 10240)  // zero xfc (840*64 f32)
      ((float4*)xfc)[i] = make_float4(0.f, 0.f, 0.f, 0.f);
    for (int i = gid; i < 131072; i += 10240) {  // split-cast out_w (lo = RNE residual)
      float4 v = ((const float4*)out_w)[i];
      unsigned h01 = cvtpk(v.x, v.y), h23 = cvtpk(v.z, v.w);
      float d0 = v.x - fromu(h01 << 16), d1 = v.y - fromu(h01 & 0xFFFF0000u);
      float d2 = v.z - fromu(h23 << 16), d3 = v.w - fromu(h23 & 0xFFFF0000u);
      uint2 hh; hh.x = h01; hh.y = h23;
      uint2 lw; lw.x = cvtpk(d0, d1); lw.y = cvtpk(d2, d3);
      ((uint2*)whi)[i] = hh;
      ((uint2*)wlo)[i] = lw;
    }
    return;
  }
  int qt = blockIdx.x;  // conv2-quarter 0..3
  // ---- stage input rows iy = 32*qt - 3 + lr, lr = 0..37 (lo = trunc residual) ----
  const float4* src = (const float4*)((n < N_CELL) ? (cell_pre + (size_t)n * 16384)
                                                   : (drug_pre + (size_t)(n - N_CELL) * 16384));
  for (int i = tid; i < 38 * 32; i += 512) {
    int lr = i >> 5, g = i & 31;
    int iy = qt * 32 - 3 + lr;
    float4 v = make_float4(0.f, 0.f, 0.f, 0.f);
    if (iy >= 0 && iy < 128) v = src[iy * 32 + g];
    unsigned h01 = cvtpk(v.x, v.y), h23 = cvtpk(v.z, v.w);
    unsigned l01 = (asu(v.x - fromu(h01 << 16)) >> 16) |
                   (asu(v.y - fromu(h01 & 0xFFFF0000u)) & 0xFFFF0000u);
    unsigned l23 = (asu(v.z - fromu(h23 << 16)) >> 16) |
                   (asu(v.w - fromu(h23 & 0xFFFF0000u)) & 0xFFFF0000u);
    uint2 hh; hh.x = h01; hh.y = h23;
    uint2 lw; lw.x = l01; lw.y = l23;
    ((uint2*)slh)[lr * 34 + g + 1] = hh;
    ((uint2*)sll)[lr * 34 + g + 1] = lw;
  }
  if (tid < 76) {  // input x-pad
    int lr = tid >> 1, g = (tid & 1) ? 33 : 0;
    ushort4 z = make_ushort4(0, 0, 0, 0);
    ((ushort4*)slh)[lr * 34 + g] = z;
    ((ushort4*)sll)[lr * 34 + g] = z;
  }
  if (tid < 36) {  // pool1-tile x-pad (cols 0 and 65)
    int r = tid >> 1, c = (tid & 1) ? 65 : 0;
    ushort4 z = make_ushort4(0, 0, 0, 0);
    ((ushort4*)p1h)[r * 66 + c] = z;
    ((ushort4*)p1l)[r * 66 + c] = z;
  }
  int wv = tid >> 6;   // 0..7
  int lane = tid & 63;
  int ml = lane & 15, q = lane >> 4;
  int oc = ml & 3, yv1 = (ml >> 2) & 1, hi = ml >> 3;
  int oc_b = ml & 7, yv2 = ml >> 3;
  float bb = b1[oc];

  // ---- load precomputed weight fragments (8 x dwordx4, L2-hot) ----
  bh8 BhE = ftab[lane],        BlE = ftab[64 + lane];
  bh8 BhO = ftab[128 + lane],  BlO = ftab[192 + lane];
  bh8 Bh20 = ftab[256 + lane], Bl20 = ftab[320 + lane];
  bh8 Bh21 = ftab[384 + lane], Bl21 = ftab[448 + lane];

  // conv2 A-offsets
  int c0 = 2 * q, c1 = 2 * q + 1;
  int c2 = 8 + 2 * q, c3 = 9 + 2 * q;
  if (c2 > 11) { c2 = 8; c3 = 9; }
  int r0 = (c0 * 86) >> 8, s0 = c0 - 3 * r0;
  int r1 = (c1 * 86) >> 8, s1 = c1 - 3 * r1;
  int r2 = (c2 * 86) >> 8, s2 = c2 - 3 * r2;
  int r3 = (c3 * 86) >> 8, s3 = c3 - 3 * r3;
  int x2 = (wv & 3) << 4;
  int off0 = r0 * 66 + x2 + ml + s0;
  int off1 = r1 * 66 + x2 + ml + s1;
  int off2 = r2 * 66 + x2 + ml + s2;
  int off3 = r3 * 66 + x2 + ml + s3;
  __syncthreads();

  // ---- conv1 phase: wave = (wv&1) x-half (32 px) x {5,5,4,4} tile rows ----
  int x0 = (wv & 1) * 16;
  int g1 = wv >> 1;  // 0..3
  int rbase = (g1 < 2) ? g1 * 5 : 10 + (g1 - 2) * 4;
  int rcnt  = (g1 < 2) ? 5 : 4;
  int Lb = x0 + ml;
  const bh4* lh4 = (const bh4*)slh;
  const bh4* ll4 = (const bh4*)sll;
#pragma unroll 1
  for (int ii = 0; ii < rcnt; ++ii) {
    int i = rbase + ii;          // pool1-tile row 0..17
    int base = (2 * i + q) * 34 + Lb;
    bh4 g0h = lh4[base], g1h = lh4[base + 1], g2h = lh4[base + 2];
    bh4 g0l = ll4[base], g1l = ll4[base + 1], g2l = ll4[base + 2];
    BH8U aeh, ael, aoh, aol;
    aeh.s.lo = g0h; aeh.s.hi = g1h;
    ael.s.lo = g0l; ael.s.hi = g1l;
    aoh.s.lo = g1h; aoh.s.hi = g2h;
    aol.s.lo = g1l; aol.s.hi = g2l;
    f32x4 de = {0.f, 0.f, 0.f, 0.f}, dd = de;
    de = __builtin_amdgcn_mfma_f32_16x16x32_bf16(aeh.v, BhE, de, 0, 0, 0);
    de = __builtin_amdgcn_mfma_f32_16x16x32_bf16(aeh.v, BlE, de, 0, 0, 0);
    de = __builtin_amdgcn_mfma_f32_16x16x32_bf16(ael.v, BhE, de, 0, 0, 0);
    dd = __builtin_amdgcn_mfma_f32_16x16x32_bf16(aoh.v, BhO, dd, 0, 0, 0);
    dd = __builtin_amdgcn_mfma_f32_16x16x32_bf16(aoh.v, BlO, dd, 0, 0, 0);
    dd = __builtin_amdgcn_mfma_f32_16x16x32_bf16(aol.v, BhO, dd, 0, 0, 0);
    int pr = qt * 16 - 1 + i;    // global pool1 row (halo rows may be out of range)
    bool inr = (pr >= 0 && pr < 64);
    float t, t2, v0, v1, v2, v3;
    t = fmaxf(de[0], dd[0]); t2 = __shfl_xor(t, 4); v0 = fmaxf(fmaxf(t, t2) + bb, 0.f);
    t = fmaxf(de[1], dd[1]); t2 = __shfl_xor(t, 4); v1 = fmaxf(fmaxf(t, t2) + bb, 0.f);
    t = fmaxf(de[2], dd[2]); t2 = __shfl_xor(t, 4); v2 = fmaxf(fmaxf(t, t2) + bb, 0.f);
    t = fmaxf(de[3], dd[3]); t2 = __shfl_xor(t, 4); v3 = fmaxf(fmaxf(t, t2) + bb, 0.f);
    if (!inr) { v0 = 0.f; v1 = 0.f; v2 = 0.f; v3 = 0.f; }
    unsigned pk01 = cvtpk(v0, v1), pk23 = cvtpk(v2, v3);
    if (yv1 == 0) {
      unsigned l0 = asu(v0 - fromu(pk01 << 16)) >> 16;
      unsigned l1 = asu(v1 - fromu(pk01 & 0xFFFF0000u)) >> 16;
      unsigned l2 = asu(v2 - fromu(pk23 << 16)) >> 16;
      unsigned l3 = asu(v3 - fromu(pk23 & 0xFFFF0000u)) >> 16;
      int idx = (i * 66 + 2 * (x0 + q * 4) + hi + 1) * 4 + oc;
      p1h[idx] = (unsigned short)pk01;              p1l[idx] = (unsigned short)l0;
      p1h[idx + 8] = (unsigned short)(pk01 >> 16);  p1l[idx + 8] = (unsigned short)l1;
      p1h[idx + 16] = (unsigned short)pk23;         p1l[idx + 16] = (unsigned short)l2;
      p1h[idx + 24] = (unsigned short)(pk23 >> 16); p1l[idx + 24] = (unsigned short)l3;
    }
  }
  __syncthreads();

  // ---- conv2 phase: wave = (wv&3) x-strip x 4 rp rows ----
  int rp0 = (wv >> 2) * 4;
  const bh4* ph4 = (const bh4*)p1h;
  const bh4* pl4 = (const bh4*)p1l;
#pragma unroll 1
  for (int rr = 0; rr < 4; ++rr) {
    int rp = rp0 + rr;
    int base2 = 2 * rp * 66;
    BH8U ah0, al0, ah1, al1;
    ah0.s.lo = ph4[base2 + off0]; ah0.s.hi = ph4[base2 + off1];
    al0.s.lo = pl4[base2 + off0]; al0.s.hi = pl4[base2 + off1];
    if (q < 2) {
      ah1.s.lo = ph4[base2 + off2]; ah1.s.hi = ph4[base2 + off3];
      al1.s.lo = pl4[base2 + off2]; al1.s.hi = pl4[base2 + off3];
    } else {
#pragma unroll
      for (int j = 0; j < 8; ++j) { ah1.v[j] = 0; al1.v[j] = 0; }
      if (q == 2) ah1.v[0] = (short)0x3F80;  // bf16 1.0 -> bias row k=48
    }
    f32x4 accA = {0.f, 0.f, 0.f, 0.f}, accB = accA;
    accA = __builtin_amdgcn_mfma_f32_16x16x32_bf16(ah0.v, Bh20, accA, 0, 0, 0);
    accA = __builtin_amdgcn_mfma_f32_16x16x32_bf16(ah0.v, Bl20, accA, 0, 0, 0);
    accA = __builtin_amdgcn_mfma_f32_16x16x32_bf16(al0.v, Bh20, accA, 0, 0, 0);
    accB = __builtin_amdgcn_mfma_f32_16x16x32_bf16(ah1.v, Bh21, accB, 0, 0, 0);
    accB = __builtin_amdgcn_mfma_f32_16x16x32_bf16(ah1.v, Bl21, accB, 0, 0, 0);
    accB = __builtin_amdgcn_mfma_f32_16x16x32_bf16(al1.v, Bh21, accB, 0, 0, 0);
    float d0 = accA[0] + accB[0], d1 = accA[1] + accB[1];
    float d2 = accA[2] + accB[2], d3 = accA[3] + accB[3];
    float m0 = fmaxf(d0, d1), m1 = fmaxf(d2, d3);
    float o0 = __shfl_xor(m0, 8), o1 = __shfl_xor(m1, 8);
    m0 = fmaxf(fmaxf(m0, o0), 0.f);
    m1 = fmaxf(fmaxf(m1, o1), 0.f);
    unsigned pk = cvtpk(m0, m1);  // [h1:h0]
    if (yv2 == 0) {
      float e0 = m0 - fromu(pk << 16), e1 = m1 - fromu(pk & 0xFFFF0000u);
      unsigned lw = cvtpk(e0, e1);  // RNE lo, [l1:l0]
      int PR = qt * 8 + rp;
      unsigned ui = (unsigned)n * 4096u + (unsigned)oc_b * 512u +
                    (unsigned)PR * 16u + (unsigned)(x2 >> 2) + (unsigned)q;
      ((unsigned*)pool2h)[ui] = pk;
      ((unsigned*)pool2l)[ui] = lw;
    }
  }
}

// ---------------- FC: split-bf16 MFMA GEMM, M=840 N=64, K chunks of 256 ----------------
__global__ __launch_bounds__(64) void k_fc(
    const unsigned short* __restrict__ pool2h, const unsigned short* __restrict__ pool2l,
    const unsigned short* __restrict__ whi, const unsigned short* __restrict__ wlo,
    float* __restrict__ xfc) {
  int mt = blockIdx.x, kc = blockIdx.y;
  int lane = threadIdx.x;
  int ml = lane & 15, q = lane >> 4;
  int row = mt * 16 + ml; if (row > N_ITEM - 1) row = N_ITEM - 1;
  size_t k0 = (size_t)kc * 256 + q * 8;
  const bh8* Ah = (const bh8*)(pool2h + (size_t)row * 8192 + k0);
  const bh8* Al = (const bh8*)(pool2l + (size_t)row * 8192 + k0);
  const bh8* Bh[4], * Bl[4];
#pragma unroll
  for (int nb = 0; nb < 4; ++nb) {
    Bh[nb] = (const bh8*)(whi + (size_t)(nb * 16 + ml) * 8192 + k0);
    Bl[nb] = (const bh8*)(wlo + (size_t)(nb * 16 + ml) * 8192 + k0);
  }
  f32x4 acc[4];
#pragma unroll
  for (int nb = 0; nb < 4; ++nb) acc[nb] = (f32x4){0.f, 0.f, 0.f, 0.f};
#pragma unroll
  for (int st = 0; st < 8; ++st) {
    bh8 ah = Ah[st * 4], al = Al[st * 4];
#pragma unroll
    for (int nb = 0; nb < 4; ++nb) {
      bh8 bhv = Bh[nb][st * 4], blv = Bl[nb][st * 4];
      acc[nb] = __builtin_amdgcn_mfma_f32_16x16x32_bf16(ah, bhv, acc[nb], 0, 0, 0);
      acc[nb] = __builtin_amdgcn_mfma_f32_16x16x32_bf16(ah, blv, acc[nb], 0, 0, 0);
      acc[nb] = __builtin_amdgcn_mfma_f32_16x16x32_bf16(al, bhv, acc[nb], 0, 0, 0);
    }
  }
#pragma unroll
  for (int r = 0; r < 4; ++r) {
    int mr = mt * 16 + q * 4 + r;
    if (mr < N_ITEM) {
      float* dst = xfc + (size_t)mr * 64 + ml;
#pragma unroll
      for (int nb = 0; nb < 4; ++nb) atomicAdd(dst + nb * 16, acc[nb][r]);
    }
  }
}

// ---------------- per-group, per-column batch norm (ddof=1) ----------------
__global__ __launch_bounds__(256) void k_norm(
    const float* __restrict__ xfc, float* __restrict__ item) {
  __shared__ float red[256];
  int grp = blockIdx.x >> 6;
  int o = blockIdx.x & 63;
  int base = grp ? N_CELL : 0;
  int N = grp ? N_DRUG : N_CELL;
  int tid = threadIdx.x;
  float s = 0.f;
  for (int i = tid; i < N; i += 256) s += xfc[(size_t)(base + i) * 64 + o];
  red[tid] = s; __syncthreads();
  for (int w = 128; w > 0; w >>= 1) { if (tid < w) red[tid] += red[tid + w]; __syncthreads(); }
  float mean = red[0] / (float)N;
  __syncthreads();
  float sq = 0.f;
  for (int i = tid; i < N; i += 256) {
    float d = xfc[(size_t)(base + i) * 64 + o] - mean;
    sq += d * d;
  }
  red[tid] = sq; __syncthreads();
  for (int w = 128; w > 0; w >>= 1) { if (tid < w) red[tid] += red[tid + w]; __syncthreads(); }
  float inv_std = 1.f / sqrtf(red[0] / (float)(N - 1));
  for (int i = tid; i < N; i += 256)
    item[(size_t)(base + i) * 64 + o] = (xfc[(size_t)(base + i) * 64 + o] - mean) * inv_std;
}

// ---------------- interact: both hops concurrent (512 thr) + agg GEMV + cell V ----------------
__global__ __launch_bounds__(512) void k_interact(
    const int* __restrict__ cell_nbr, const int* __restrict__ drug_nbr,
    const float* __restrict__ protein, const float* __restrict__ item,
    const float* __restrict__ agg_w, const float* __restrict__ agg_b,
    const float* __restrict__ comb_w, float* __restrict__ emb,
    float* __restrict__ V) {
  __shared__ float pb[2][128 * 65];
  __shared__ float item_s[64];
  __shared__ float sc[2][128];
  __shared__ float hop_out[128];
  __shared__ float red[512];
  __shared__ float emb_f[64];
  int n = blockIdx.x;
  int tid = threadIdx.x;
  int ht = tid >> 8;      // hop 0/1
  int t = tid & 255;      // thread within hop
  const int* nbr = (n < N_CELL) ? (cell_nbr + (size_t)n * 256)
                                : (drug_nbr + (size_t)(n - N_CELL) * 256);
  if (tid < 64) item_s[tid] = item[(size_t)n * 64 + tid];
  __syncthreads();
  for (int e = t; e < 8192; e += 256) {
    int k = e >> 6, d = e & 63;
    int idx = nbr[ht * 128 + k];
    pb[ht][k * 65 + d] = protein[(size_t)idx * 64 + d];
  }
  __syncthreads();
  {  // scores: 2 threads per k
    int k = t >> 1, halfd = t & 1;
    int d0 = halfd * 32;
    float p = 0.f;
#pragma unroll
    for (int d = 0; d < 32; ++d) p += item_s[d0 + d] * pb[ht][k * 65 + d0 + d];
    p += __shfl_xor(p, 1);
    if (halfd == 0) sc[ht][k] = p;
  }
  __syncthreads();
  if (t < 64) {  // softmax over 128 (waves 0 and 4)
    float a = sc[ht][t], b = sc[ht][t + 64];
    float m = fmaxf(a, b);
#pragma unroll
    for (int off = 32; off > 0; off >>= 1) m = fmaxf(m, __shfl_xor(m, off));
    float e0 = __expf(a - m), e1 = __expf(b - m);
    float s = e0 + e1;
#pragma unroll
    for (int off = 32; off > 0; off >>= 1) s += __shfl_xor(s, off);
    float inv = 1.f / s;
    sc[ht][t] = e0 * inv; sc[ht][t + 64] = e1 * inv;
  }
  __syncthreads();
  {  // PV: 4 k-chunks x 64 d
    int d = t & 63, kq = t >> 6;
    float p = 0.f;
#pragma unroll
    for (int k = 0; k < 32; ++k) {
      int kk = kq * 32 + k;
      p += sc[ht][kk] * pb[ht][kk * 65 + d];
    }
    red[tid] = p;
  }
  __syncthreads();
  if (t < 64)
    hop_out[ht * 64 + t] = red[ht * 256 + t] + red[ht * 256 + t + 64] +
                           red[ht * 256 + t + 128] + red[ht * 256 + t + 192];
  __syncthreads();
  {  // agg GEMV: 8 j-chunks of 16
    int o = tid & 63, jq = tid >> 6;
    float p = 0.f;
#pragma unroll
    for (int j = 0; j < 16; ++j) {
      int jj = jq * 16 + j;
      p += hop_out[jj] * agg_w[(size_t)o * 128 + jj];
    }
    red[tid] = p;
  }
  __syncthreads();
  if (tid < 64) {
    float ev = red[tid] + red[tid + 64] + red[tid + 128] + red[tid + 192] +
               red[tid + 256] + red[tid + 320] + red[tid + 384] + red[tid + 448] +
               agg_b[tid];
    emb[(size_t)n * 64 + tid] = ev;
    emb_f[tid] = ev;
  }
  if (n < N_CELL) {  // fused k_cellv: V[n] = comb_w^T @ emb[n]
    __syncthreads();
    if (tid < 128) {
      float s = 0.f;
#pragma unroll
      for (int o = 0; o < 64; ++o) s += comb_w[(size_t)o * 128 + tid] * emb_f[o];
      V[(size_t)n * 128 + tid] = s;
    }
  }
}

// ---------------- fused scoring + node reg + finalize (completion counter) ----------------
__global__ __launch_bounds__(256) void k_scoreall(
    const int* __restrict__ data, const int* __restrict__ cell_nbr,
    const int* __restrict__ drug_nbr, const float* __restrict__ protein,
    const float* __restrict__ emb, const float* __restrict__ V,
    float* __restrict__ out, float* __restrict__ loss, unsigned* __restrict__ cnt) {
  __shared__ float red[256];
  int bx = blockIdx.x;
  int tid = threadIdx.x;
  if (bx < 1024) {
    int lane = tid & 63;
    int w = tid >> 6;
    int b = bx * 4 + w;
    int c = data[b * 3 + 0], d1 = data[b * 3 + 1], d2 = data[b * 3 + 2];
    float ce = emb[(size_t)c * 64 + lane];
    float e1 = emb[(size_t)(N_CELL + d1) * 64 + lane];
    float e2 = emb[(size_t)(N_CELL + d2) * 64 + lane];
    float v1 = V[(size_t)c * 128 + lane];
    float v2 = V[(size_t)c * 128 + 64 + lane];
    float th = e1 * v1 + e2 * v2;
    float tx = e1 * e2;
    float rg = ce * ce + e1 * e1 + e2 * e2;
#pragma unroll
    for (int off = 32; off > 0; off >>= 1) {
      th += __shfl_xor(th, off);
      tx += __shfl_xor(tx, off);
      rg += __shfl_xor(rg, off);
    }
    if (lane == 0) { out[b] = th - tx; red[w] = rg; }
    __syncthreads();
    if (tid == 0) atomicAdd(loss, 0.5f * (red[0] + red[1] + red[2] + red[3]));
  } else {
    int j = bx - 1024;
    int hop = j / 3, which = j % 3;
    int row = data[hop * 3 + which];
    const int* nbr = (which == 0) ? (cell_nbr + (size_t)row * 256)
                                  : (drug_nbr + (size_t)row * 256);
    float acc = 0.f;
    for (int e = tid; e < 16384; e += 256) {
      int k = e >> 6, d = e & 63;
      float v = protein[(size_t)nbr[k] * 64 + d];
      acc += v * v;
    }
    red[tid] = acc; __syncthreads();
    for (int w = 128; w > 0; w >>= 1) { if (tid < w) red[tid] += red[tid + w]; __syncthreads(); }
    if (tid == 0) atomicAdd(loss, 0.5f * red[0]);
  }
  if (tid == 0) {
    __threadfence();
    unsigned old = atomicAdd(cnt, 1u);
    if (old == gridDim.x - 1) {
      float L = atomicAdd(loss, 0.f);  // device-coherent read
      out[BATCH] = L * (1e-6f / 4096.f);
    }
  }
}

extern "C" void kernel_launch(void* const* d_in, const int* in_sizes, int n_in,
                              void* d_out, int out_size, void* d_ws, size_t ws_size,
                              hipStream_t stream) {
  const int*   data      = (const int*)d_in[0];
  const int*   cell_nbr  = (const int*)d_in[1];
  const int*   drug_nbr  = (const int*)d_in[2];
  const float* protein   = (const float*)d_in[3];
  const float* cell_pre  = (const float*)d_in[4];
  const float* drug_pre  = (const float*)d_in[5];
  const float* w1        = (const float*)d_in[6];
  const float* b1        = (const float*)d_in[7];
  const float* w2        = (const float*)d_in[8];
  const float* b2        = (const float*)d_in[9];
  const float* out_w     = (const float*)d_in[10];
  const float* agg_w     = (const float*)d_in[12];
  const float* agg_b     = (const float*)d_in[13];
  const float* comb_w    = (const float*)d_in[14];
  float* out = (float*)d_out;
  char* base = (char*)d_ws;
  unsigned short* pool2h  = (unsigned short*)(base + POOL2H_B);
  unsigned short* pool2l  = (unsigned short*)(base + POOL2L_B);
  unsigned short* whi     = (unsigned short*)(base + WHI_B);
  unsigned short* wlo     = (unsigned short*)(base + WLO_B);
  float* xfc              = (float*)(base + XFC_B);
  float* item             = (float*)(base + ITEM_B);
  float* emb              = (float*)(base + EMB_B);
  float* V                = (float*)(base + V_B);
  float* loss             = (float*)(base + LOSS_B);
  unsigned* cnt           = (unsigned*)(base + CNT_B);
  bh8* ftab               = (bh8*)(base + FRAG_B);

  k_prep<<<1, 64, 0, stream>>>(w1, w2, b2, ftab, loss, cnt);
  k_conv12<<<dim3(4, 845), 512, 0, stream>>>(cell_pre, drug_pre, b1, out_w, ftab,
                                             pool2h, pool2l, whi, wlo, xfc);
  k_fc<<<dim3(53, 32), 64, 0, stream>>>(pool2h, pool2l, whi, wlo, xfc);
  k_norm<<<128, 256, 0, stream>>>(xfc, item);
  k_interact<<<840, 512, 0, stream>>>(cell_nbr, drug_nbr, protein, item, agg_w, agg_b,
                                      comb_w, emb, V);
  k_scoreall<<<1030, 256, 0, stream>>>(data, cell_nbr, drug_nbr, protein, emb, V, out, loss, cnt);
}

// Round 5
// 210.369 us; speedup vs baseline: 1.2036x; 1.1291x over previous
//
#include <hip/hip_runtime.h>
#include <hip/hip_bf16.h>
#include <math.h>

#define N_CELL 76
#define N_DRUG 764
#define N_ITEM 840
#define BATCH  4096

// ws layout (byte offsets)
#define POOL2H_B 0u
#define POOL2L_B 13762560u
#define WHI_B    27525120u
#define WLO_B    28573696u
#define XFC_B    29622272u
#define ITEM_B   29837312u
#define EMB_B    30052352u
#define V_B      30267392u
#define LOSS_B   30306304u
#define CNT_B    30306368u
#define FRAG_B   30306432u   // 8 sets x 64 lanes x 16B = 8KB

typedef short bh8 __attribute__((ext_vector_type(8)));
typedef short bh4 __attribute__((ext_vector_type(4)));
typedef float f32x4 __attribute__((ext_vector_type(4)));

static __device__ inline unsigned short f2bf(float f) {
  union { float f; unsigned u; } v; v.f = f;
  unsigned r = v.u + 0x7FFFu + ((v.u >> 16) & 1u);  // RNE (no NaN inputs here)
  return (unsigned short)(r >> 16);
}
static __device__ inline float bf2f(unsigned short h) {
  union { unsigned u; float f; } v; v.u = ((unsigned)h) << 16;
  return v.f;
}
// lo residual via truncation (residual <= 2^-9|a|, trunc err <= 2^-17|a|)
static __device__ inline unsigned short f2bf_lo(float f, unsigned short h) {
  union { float f; unsigned u; } a; a.f = f - bf2f(h);
  return (unsigned short)(a.u >> 16);
}
// hw packed RNE f32->bf16 (gfx950): dst = [bf16(b) : bf16(a)]
static __device__ inline unsigned cvtpk(float a, float b) {
  unsigned r;
  asm("v_cvt_pk_bf16_f32 %0, %1, %2" : "=v"(r) : "v"(a), "v"(b));
  return r;
}
static __device__ inline float fromu(unsigned u) {
  union { unsigned u; float f; } v; v.u = u; return v.f;
}
static __device__ inline unsigned asu(float f) {
  union { float f; unsigned u; } v; v.f = f; return v.u;
}

union BH8U { bh8 v; struct { bh4 lo, hi; } s; };

// ---------------- precompute per-lane weight fragments (once) ----------------
__global__ __launch_bounds__(64) void k_prep(
    const float* __restrict__ w1, const float* __restrict__ w2,
    const float* __restrict__ b2, bh8* __restrict__ ftab,
    float* __restrict__ loss, unsigned* __restrict__ cnt) {
  int lane = threadIdx.x & 63;
  int ml = lane & 15, q = lane >> 4;
  int oc = ml & 3, yv1 = (ml >> 2) & 1, hi = ml >> 3;
  bh8 BhE, BlE, BhO, BlO;
  {
    int kr = q - yv1;
    bool krok = (kr >= 0 && kr <= 2);
#pragma unroll
    for (int j = 0; j < 8; ++j) {
      float ve = 0.f, vo = 0.f;
      if (krok) {
        int kse = j - 3 - 2 * hi;   // even phases 0/2
        int kso = j - 2 * hi;       // odd  phases 1/3
        if (kse >= 0 && kse <= 2) ve = w1[oc * 9 + kr * 3 + kse];
        if (kso >= 0 && kso <= 2) vo = w1[oc * 9 + kr * 3 + kso];
      }
      unsigned short he = f2bf(ve), ho = f2bf(vo);
      BhE[j] = (short)he; BlE[j] = (short)f2bf_lo(ve, he);
      BhO[j] = (short)ho; BlO[j] = (short)f2bf_lo(vo, ho);
    }
  }
  int oc_b = ml & 7, yv2 = ml >> 3;
  bh8 Bh2[2], Bl2[2];
#pragma unroll
  for (int ch = 0; ch < 2; ++ch) {
#pragma unroll
    for (int j = 0; j < 8; ++j) {
      int kg = ch * 32 + q * 8 + j;
      float v = 0.f;
      if (kg < 48) {
        int r = kg / 12, rem = kg - r * 12;
        int ks = rem >> 2, ic = rem & 3;
        int kr = r - yv2;
        if (kr >= 0 && kr <= 2) v = w2[(oc_b * 4 + ic) * 9 + kr * 3 + ks];
      } else if (kg == 48) {
        v = b2[oc_b];
      }
      unsigned short h = f2bf(v);
      Bh2[ch][j] = (short)h;
      Bl2[ch][j] = (short)f2bf_lo(v, h);
    }
  }
  ftab[lane] = BhE;          ftab[64 + lane] = BlE;
  ftab[128 + lane] = BhO;    ftab[192 + lane] = BlO;
  ftab[256 + lane] = Bh2[0]; ftab[320 + lane] = Bl2[0];
  ftab[384 + lane] = Bh2[1]; ftab[448 + lane] = Bl2[1];
  if (lane == 0) { *loss = 0.f; *cnt = 0u; }
}

// ---------------- fused conv1+pool1+conv2+pool2 (quarter blocks, 8 waves) ----------------
__global__ __launch_bounds__(512) void k_conv12(
    const float* __restrict__ cell_pre, const float* __restrict__ drug_pre,
    const float* __restrict__ b1, const float* __restrict__ out_w,
    const bh8* __restrict__ ftab,
    unsigned short* __restrict__ pool2h, unsigned short* __restrict__ pool2l,
    unsigned short* __restrict__ whi, unsigned short* __restrict__ wlo,
    float* __restrict__ xfc) {
  __shared__ unsigned short slh[38 * 34 * 4];
  __shared__ unsigned short sll[38 * 34 * 4];
  __shared__ unsigned short p1h[18 * 66 * 4];
  __shared__ unsigned short p1l[18 * 66 * 4];
  int n = blockIdx.y;
  int tid = threadIdx.x;
  if (n >= 840) {
    // ---- cast/zero blocks: 5 y-rows x 4 = 20 blocks, 10240 threads ----
    int cb = (n - 840) * 4 + blockIdx.x;
    int gid = cb * 512 + tid;  // 0..10239
    for (int i = gid; i < 13440; i += 10240)  // zero xfc (840*64 f32)
      ((float4*)xfc)[i] = make_float4(0.f, 0.f, 0.f, 0.f);
    for (int i = gid; i < 131072; i += 10240) {  // split-cast out_w (lo = RNE residual)
      float4 v = ((const float4*)out_w)[i];
      unsigned h01 = cvtpk(v.x, v.y), h23 = cvtpk(v.z, v.w);
      float d0 = v.x - fromu(h01 << 16), d1 = v.y - fromu(h01 & 0xFFFF0000u);
      float d2 = v.z - fromu(h23 << 16), d3 = v.w - fromu(h23 & 0xFFFF0000u);
      uint2 hh; hh.x = h01; hh.y = h23;
      uint2 lw; lw.x = cvtpk(d0, d1); lw.y = cvtpk(d2, d3);
      ((uint2*)whi)[i] = hh;
      ((uint2*)wlo)[i] = lw;
    }
    return;
  }
  int qt = blockIdx.x;  // conv2-quarter 0..3
  // ---- stage input rows iy = 32*qt - 3 + lr, lr = 0..37 (lo = trunc residual) ----
  const float4* src = (const float4*)((n < N_CELL) ? (cell_pre + (size_t)n * 16384)
                                                   : (drug_pre + (size_t)(n - N_CELL) * 16384));
  for (int i = tid; i < 38 * 32; i += 512) {
    int lr = i >> 5, g = i & 31;
    int iy = qt * 32 - 3 + lr;
    float4 v = make_float4(0.f, 0.f, 0.f, 0.f);
    if (iy >= 0 && iy < 128) v = src[iy * 32 + g];
    unsigned h01 = cvtpk(v.x, v.y), h23 = cvtpk(v.z, v.w);
    unsigned l01 = (asu(v.x - fromu(h01 << 16)) >> 16) |
                   (asu(v.y - fromu(h01 & 0xFFFF0000u)) & 0xFFFF0000u);
    unsigned l23 = (asu(v.z - fromu(h23 << 16)) >> 16) |
                   (asu(v.w - fromu(h23 & 0xFFFF0000u)) & 0xFFFF0000u);
    uint2 hh; hh.x = h01; hh.y = h23;
    uint2 lw; lw.x = l01; lw.y = l23;
    ((uint2*)slh)[lr * 34 + g + 1] = hh;
    ((uint2*)sll)[lr * 34 + g + 1] = lw;
  }
  if (tid < 76) {  // input x-pad
    int lr = tid >> 1, g = (tid & 1) ? 33 : 0;
    ushort4 z = make_ushort4(0, 0, 0, 0);
    ((ushort4*)slh)[lr * 34 + g] = z;
    ((ushort4*)sll)[lr * 34 + g] = z;
  }
  if (tid < 36) {  // pool1-tile x-pad (cols 0 and 65)
    int r = tid >> 1, c = (tid & 1) ? 65 : 0;
    ushort4 z = make_ushort4(0, 0, 0, 0);
    ((ushort4*)p1h)[r * 66 + c] = z;
    ((ushort4*)p1l)[r * 66 + c] = z;
  }
  int wv = tid >> 6;   // 0..7
  int lane = tid & 63;
  int ml = lane & 15, q = lane >> 4;
  int oc = ml & 3, yv1 = (ml >> 2) & 1, hi = ml >> 3;
  int oc_b = ml & 7, yv2 = ml >> 3;
  float bb = b1[oc];

  // ---- load precomputed weight fragments (8 x dwordx4, L2-hot) ----
  bh8 BhE = ftab[lane],        BlE = ftab[64 + lane];
  bh8 BhO = ftab[128 + lane],  BlO = ftab[192 + lane];
  bh8 Bh20 = ftab[256 + lane], Bl20 = ftab[320 + lane];
  bh8 Bh21 = ftab[384 + lane], Bl21 = ftab[448 + lane];

  // conv2 A-offsets
  int c0 = 2 * q, c1 = 2 * q + 1;
  int c2 = 8 + 2 * q, c3 = 9 + 2 * q;
  if (c2 > 11) { c2 = 8; c3 = 9; }
  int r0 = (c0 * 86) >> 8, s0 = c0 - 3 * r0;
  int r1 = (c1 * 86) >> 8, s1 = c1 - 3 * r1;
  int r2 = (c2 * 86) >> 8, s2 = c2 - 3 * r2;
  int r3 = (c3 * 86) >> 8, s3 = c3 - 3 * r3;
  int x2 = (wv & 3) << 4;
  int off0 = r0 * 66 + x2 + ml + s0;
  int off1 = r1 * 66 + x2 + ml + s1;
  int off2 = r2 * 66 + x2 + ml + s2;
  int off3 = r3 * 66 + x2 + ml + s3;
  __syncthreads();

  // ---- conv1 phase: wave = (wv&1) x-half (32 px) x {5,5,4,4} tile rows ----
  int x0 = (wv & 1) * 16;
  int g1 = wv >> 1;  // 0..3
  int rbase = (g1 < 2) ? g1 * 5 : 10 + (g1 - 2) * 4;
  int rcnt  = (g1 < 2) ? 5 : 4;
  int Lb = x0 + ml;
  const bh4* lh4 = (const bh4*)slh;
  const bh4* ll4 = (const bh4*)sll;
#pragma unroll 1
  for (int ii = 0; ii < rcnt; ++ii) {
    int i = rbase + ii;          // pool1-tile row 0..17
    int base = (2 * i + q) * 34 + Lb;
    bh4 g0h = lh4[base], g1h = lh4[base + 1], g2h = lh4[base + 2];
    bh4 g0l = ll4[base], g1l = ll4[base + 1], g2l = ll4[base + 2];
    BH8U aeh, ael, aoh, aol;
    aeh.s.lo = g0h; aeh.s.hi = g1h;
    ael.s.lo = g0l; ael.s.hi = g1l;
    aoh.s.lo = g1h; aoh.s.hi = g2h;
    aol.s.lo = g1l; aol.s.hi = g2l;
    f32x4 de = {0.f, 0.f, 0.f, 0.f}, dd = de;
    de = __builtin_amdgcn_mfma_f32_16x16x32_bf16(aeh.v, BhE, de, 0, 0, 0);
    de = __builtin_amdgcn_mfma_f32_16x16x32_bf16(aeh.v, BlE, de, 0, 0, 0);
    de = __builtin_amdgcn_mfma_f32_16x16x32_bf16(ael.v, BhE, de, 0, 0, 0);
    dd = __builtin_amdgcn_mfma_f32_16x16x32_bf16(aoh.v, BhO, dd, 0, 0, 0);
    dd = __builtin_amdgcn_mfma_f32_16x16x32_bf16(aoh.v, BlO, dd, 0, 0, 0);
    dd = __builtin_amdgcn_mfma_f32_16x16x32_bf16(aol.v, BhO, dd, 0, 0, 0);
    int pr = qt * 16 - 1 + i;    // global pool1 row (halo rows may be out of range)
    bool inr = (pr >= 0 && pr < 64);
    float t, t2, v0, v1, v2, v3;
    t = fmaxf(de[0], dd[0]); t2 = __shfl_xor(t, 4); v0 = fmaxf(fmaxf(t, t2) + bb, 0.f);
    t = fmaxf(de[1], dd[1]); t2 = __shfl_xor(t, 4); v1 = fmaxf(fmaxf(t, t2) + bb, 0.f);
    t = fmaxf(de[2], dd[2]); t2 = __shfl_xor(t, 4); v2 = fmaxf(fmaxf(t, t2) + bb, 0.f);
    t = fmaxf(de[3], dd[3]); t2 = __shfl_xor(t, 4); v3 = fmaxf(fmaxf(t, t2) + bb, 0.f);
    if (!inr) { v0 = 0.f; v1 = 0.f; v2 = 0.f; v3 = 0.f; }
    unsigned pk01 = cvtpk(v0, v1), pk23 = cvtpk(v2, v3);
    if (yv1 == 0) {
      unsigned l0 = asu(v0 - fromu(pk01 << 16)) >> 16;
      unsigned l1 = asu(v1 - fromu(pk01 & 0xFFFF0000u)) >> 16;
      unsigned l2 = asu(v2 - fromu(pk23 << 16)) >> 16;
      unsigned l3 = asu(v3 - fromu(pk23 & 0xFFFF0000u)) >> 16;
      int idx = (i * 66 + 2 * (x0 + q * 4) + hi + 1) * 4 + oc;
      p1h[idx] = (unsigned short)pk01;              p1l[idx] = (unsigned short)l0;
      p1h[idx + 8] = (unsigned short)(pk01 >> 16);  p1l[idx + 8] = (unsigned short)l1;
      p1h[idx + 16] = (unsigned short)pk23;         p1l[idx + 16] = (unsigned short)l2;
      p1h[idx + 24] = (unsigned short)(pk23 >> 16); p1l[idx + 24] = (unsigned short)l3;
    }
  }
  __syncthreads();

  // ---- conv2 phase: wave = (wv&3) x-strip x 4 rp rows ----
  int rp0 = (wv >> 2) * 4;
  const bh4* ph4 = (const bh4*)p1h;
  const bh4* pl4 = (const bh4*)p1l;
#pragma unroll 1
  for (int rr = 0; rr < 4; ++rr) {
    int rp = rp0 + rr;
    int base2 = 2 * rp * 66;
    BH8U ah0, al0, ah1, al1;
    ah0.s.lo = ph4[base2 + off0]; ah0.s.hi = ph4[base2 + off1];
    al0.s.lo = pl4[base2 + off0]; al0.s.hi = pl4[base2 + off1];
    if (q < 2) {
      ah1.s.lo = ph4[base2 + off2]; ah1.s.hi = ph4[base2 + off3];
      al1.s.lo = pl4[base2 + off2]; al1.s.hi = pl4[base2 + off3];
    } else {
#pragma unroll
      for (int j = 0; j < 8; ++j) { ah1.v[j] = 0; al1.v[j] = 0; }
      if (q == 2) ah1.v[0] = (short)0x3F80;  // bf16 1.0 -> bias row k=48
    }
    f32x4 accA = {0.f, 0.f, 0.f, 0.f}, accB = accA;
    accA = __builtin_amdgcn_mfma_f32_16x16x32_bf16(ah0.v, Bh20, accA, 0, 0, 0);
    accA = __builtin_amdgcn_mfma_f32_16x16x32_bf16(ah0.v, Bl20, accA, 0, 0, 0);
    accA = __builtin_amdgcn_mfma_f32_16x16x32_bf16(al0.v, Bh20, accA, 0, 0, 0);
    accB = __builtin_amdgcn_mfma_f32_16x16x32_bf16(ah1.v, Bh21, accB, 0, 0, 0);
    accB = __builtin_amdgcn_mfma_f32_16x16x32_bf16(ah1.v, Bl21, accB, 0, 0, 0);
    accB = __builtin_amdgcn_mfma_f32_16x16x32_bf16(al1.v, Bh21, accB, 0, 0, 0);
    float d0 = accA[0] + accB[0], d1 = accA[1] + accB[1];
    float d2 = accA[2] + accB[2], d3 = accA[3] + accB[3];
    float m0 = fmaxf(d0, d1), m1 = fmaxf(d2, d3);
    float o0 = __shfl_xor(m0, 8), o1 = __shfl_xor(m1, 8);
    m0 = fmaxf(fmaxf(m0, o0), 0.f);
    m1 = fmaxf(fmaxf(m1, o1), 0.f);
    unsigned pk = cvtpk(m0, m1);  // [h1:h0]
    if (yv2 == 0) {
      float e0 = m0 - fromu(pk << 16), e1 = m1 - fromu(pk & 0xFFFF0000u);
      unsigned lw = cvtpk(e0, e1);  // RNE lo, [l1:l0]
      int PR = qt * 8 + rp;
      unsigned ui = (unsigned)n * 4096u + (unsigned)oc_b * 512u +
                    (unsigned)PR * 16u + (unsigned)(x2 >> 2) + (unsigned)q;
      ((unsigned*)pool2h)[ui] = pk;
      ((unsigned*)pool2l)[ui] = lw;
    }
  }
}

// ---------------- FC: split-bf16 MFMA GEMM, M=840 N=64, K chunks of 256 ----------------
__global__ __launch_bounds__(64) void k_fc(
    const unsigned short* __restrict__ pool2h, const unsigned short* __restrict__ pool2l,
    const unsigned short* __restrict__ whi, const unsigned short* __restrict__ wlo,
    float* __restrict__ xfc) {
  int mt = blockIdx.x, kc = blockIdx.y;
  int lane = threadIdx.x;
  int ml = lane & 15, q = lane >> 4;
  int row = mt * 16 + ml; if (row > N_ITEM - 1) row = N_ITEM - 1;
  size_t k0 = (size_t)kc * 256 + q * 8;
  const bh8* Ah = (const bh8*)(pool2h + (size_t)row * 8192 + k0);
  const bh8* Al = (const bh8*)(pool2l + (size_t)row * 8192 + k0);
  const bh8* Bh[4], * Bl[4];
#pragma unroll
  for (int nb = 0; nb < 4; ++nb) {
    Bh[nb] = (const bh8*)(whi + (size_t)(nb * 16 + ml) * 8192 + k0);
    Bl[nb] = (const bh8*)(wlo + (size_t)(nb * 16 + ml) * 8192 + k0);
  }
  f32x4 acc[4];
#pragma unroll
  for (int nb = 0; nb < 4; ++nb) acc[nb] = (f32x4){0.f, 0.f, 0.f, 0.f};
#pragma unroll
  for (int st = 0; st < 8; ++st) {
    bh8 ah = Ah[st * 4], al = Al[st * 4];
#pragma unroll
    for (int nb = 0; nb < 4; ++nb) {
      bh8 bhv = Bh[nb][st * 4], blv = Bl[nb][st * 4];
      acc[nb] = __builtin_amdgcn_mfma_f32_16x16x32_bf16(ah, bhv, acc[nb], 0, 0, 0);
      acc[nb] = __builtin_amdgcn_mfma_f32_16x16x32_bf16(ah, blv, acc[nb], 0, 0, 0);
      acc[nb] = __builtin_amdgcn_mfma_f32_16x16x32_bf16(al, bhv, acc[nb], 0, 0, 0);
    }
  }
#pragma unroll
  for (int r = 0; r < 4; ++r) {
    int mr = mt * 16 + q * 4 + r;
    if (mr < N_ITEM) {
      float* dst = xfc + (size_t)mr * 64 + ml;
#pragma unroll
      for (int nb = 0; nb < 4; ++nb) atomicAdd(dst + nb * 16, acc[nb][r]);
    }
  }
}

// ---------------- per-group, per-column batch norm (ddof=1) ----------------
__global__ __launch_bounds__(256) void k_norm(
    const float* __restrict__ xfc, float* __restrict__ item) {
  __shared__ float red[256];
  int grp = blockIdx.x >> 6;
  int o = blockIdx.x & 63;
  int base = grp ? N_CELL : 0;
  int N = grp ? N_DRUG : N_CELL;
  int tid = threadIdx.x;
  float s = 0.f;
  for (int i = tid; i < N; i += 256) s += xfc[(size_t)(base + i) * 64 + o];
  red[tid] = s; __syncthreads();
  for (int w = 128; w > 0; w >>= 1) { if (tid < w) red[tid] += red[tid + w]; __syncthreads(); }
  float mean = red[0] / (float)N;
  __syncthreads();
  float sq = 0.f;
  for (int i = tid; i < N; i += 256) {
    float d = xfc[(size_t)(base + i) * 64 + o] - mean;
    sq += d * d;
  }
  red[tid] = sq; __syncthreads();
  for (int w = 128; w > 0; w >>= 1) { if (tid < w) red[tid] += red[tid + w]; __syncthreads(); }
  float inv_std = 1.f / sqrtf(red[0] / (float)(N - 1));
  for (int i = tid; i < N; i += 256)
    item[(size_t)(base + i) * 64 + o] = (xfc[(size_t)(base + i) * 64 + o] - mean) * inv_std;
}

// ---------------- interact: both hops concurrent (512 thr) + agg GEMV + cell V ----------------
__global__ __launch_bounds__(512) void k_interact(
    const int* __restrict__ cell_nbr, const int* __restrict__ drug_nbr,
    const float* __restrict__ protein, const float* __restrict__ item,
    const float* __restrict__ agg_w, const float* __restrict__ agg_b,
    const float* __restrict__ comb_w, float* __restrict__ emb,
    float* __restrict__ V) {
  __shared__ float pb[2][128 * 65];
  __shared__ float item_s[64];
  __shared__ float sc[2][128];
  __shared__ float hop_out[128];
  __shared__ float red[512];
  __shared__ float emb_f[64];
  int n = blockIdx.x;
  int tid = threadIdx.x;
  int ht = tid >> 8;      // hop 0/1
  int t = tid & 255;      // thread within hop
  const int* nbr = (n < N_CELL) ? (cell_nbr + (size_t)n * 256)
                                : (drug_nbr + (size_t)(n - N_CELL) * 256);
  if (tid < 64) item_s[tid] = item[(size_t)n * 64 + tid];
  __syncthreads();
  for (int e = t; e < 8192; e += 256) {
    int k = e >> 6, d = e & 63;
    int idx = nbr[ht * 128 + k];
    pb[ht][k * 65 + d] = protein[(size_t)idx * 64 + d];
  }
  __syncthreads();
  {  // scores: 2 threads per k
    int k = t >> 1, halfd = t & 1;
    int d0 = halfd * 32;
    float p = 0.f;
#pragma unroll
    for (int d = 0; d < 32; ++d) p += item_s[d0 + d] * pb[ht][k * 65 + d0 + d];
    p += __shfl_xor(p, 1);
    if (halfd == 0) sc[ht][k] = p;
  }
  __syncthreads();
  if (t < 64) {  // softmax over 128 (waves 0 and 4)
    float a = sc[ht][t], b = sc[ht][t + 64];
    float m = fmaxf(a, b);
#pragma unroll
    for (int off = 32; off > 0; off >>= 1) m = fmaxf(m, __shfl_xor(m, off));
    float e0 = __expf(a - m), e1 = __expf(b - m);
    float s = e0 + e1;
#pragma unroll
    for (int off = 32; off > 0; off >>= 1) s += __shfl_xor(s, off);
    float inv = 1.f / s;
    sc[ht][t] = e0 * inv; sc[ht][t + 64] = e1 * inv;
  }
  __syncthreads();
  {  // PV: 4 k-chunks x 64 d
    int d = t & 63, kq = t >> 6;
    float p = 0.f;
#pragma unroll
    for (int k = 0; k < 32; ++k) {
      int kk = kq * 32 + k;
      p += sc[ht][kk] * pb[ht][kk * 65 + d];
    }
    red[tid] = p;
  }
  __syncthreads();
  if (t < 64)
    hop_out[ht * 64 + t] = red[ht * 256 + t] + red[ht * 256 + t + 64] +
                           red[ht * 256 + t + 128] + red[ht * 256 + t + 192];
  __syncthreads();
  {  // agg GEMV: 8 j-chunks of 16
    int o = tid & 63, jq = tid >> 6;
    float p = 0.f;
#pragma unroll
    for (int j = 0; j < 16; ++j) {
      int jj = jq * 16 + j;
      p += hop_out[jj] * agg_w[(size_t)o * 128 + jj];
    }
    red[tid] = p;
  }
  __syncthreads();
  if (tid < 64) {
    float ev = red[tid] + red[tid + 64] + red[tid + 128] + red[tid + 192] +
               red[tid + 256] + red[tid + 320] + red[tid + 384] + red[tid + 448] +
               agg_b[tid];
    emb[(size_t)n * 64 + tid] = ev;
    emb_f[tid] = ev;
  }
  if (n < N_CELL) {  // fused k_cellv: V[n] = comb_w^T @ emb[n]
    __syncthreads();
    if (tid < 128) {
      float s = 0.f;
#pragma unroll
      for (int o = 0; o < 64; ++o) s += comb_w[(size_t)o * 128 + tid] * emb_f[o];
      V[(size_t)n * 128 + tid] = s;
    }
  }
}

// ---------------- scoring + node reg + finalize: 70 blocks, 1 loss-atomic/block ----------------
__global__ __launch_bounds__(512) void k_scoreall(
    const int* __restrict__ data, const int* __restrict__ cell_nbr,
    const int* __restrict__ drug_nbr, const float* __restrict__ protein,
    const float* __restrict__ emb, const float* __restrict__ V,
    float* __restrict__ out, float* __restrict__ loss, unsigned* __restrict__ cnt) {
  __shared__ float red[8];
  int bx = blockIdx.x;
  int tid = threadIdx.x;
  int lane = tid & 63;
  int wv = tid >> 6;       // 0..7
  float part = 0.f;        // per-lane partial of this block's loss contribution
  if (bx < 64) {
    // ---- scoring: 8 waves x 8 items = 64 items per block ----
    int b0 = bx * 64 + wv * 8;
#pragma unroll 1
    for (int i = 0; i < 8; ++i) {
      int b = b0 + i;
      int c = data[b * 3 + 0], d1 = data[b * 3 + 1], d2 = data[b * 3 + 2];
      float ce = emb[(size_t)c * 64 + lane];
      float e1 = emb[(size_t)(N_CELL + d1) * 64 + lane];
      float e2 = emb[(size_t)(N_CELL + d2) * 64 + lane];
      float v1 = V[(size_t)c * 128 + lane];
      float v2 = V[(size_t)c * 128 + 64 + lane];
      float s = e1 * v1 + e2 * v2 - e1 * e2;   // (therapy - toxic) per-d
      part += ce * ce + e1 * e1 + e2 * e2;     // item regularization, per-lane
#pragma unroll
      for (int off = 32; off > 0; off >>= 1) s += __shfl_xor(s, off);
      if (lane == 0) out[b] = s;
    }
  } else {
    // ---- node regularization: blocks 64..69 ----
    int j = bx - 64;
    int hop = j / 3, which = j % 3;
    int row = data[hop * 3 + which];
    const int* nbr = (which == 0) ? (cell_nbr + (size_t)row * 256)
                                  : (drug_nbr + (size_t)row * 256);
    for (int e = tid; e < 16384; e += 512) {
      int k = e >> 6, d = e & 63;
      float v = protein[(size_t)nbr[k] * 64 + d];
      part += v * v;
    }
  }
  // wave reduce, then block reduce, ONE atomic per block
#pragma unroll
  for (int off = 32; off > 0; off >>= 1) part += __shfl_xor(part, off);
  if (lane == 0) red[wv] = part;
  __syncthreads();
  if (tid == 0) {
    float s = red[0] + red[1] + red[2] + red[3] + red[4] + red[5] + red[6] + red[7];
    atomicAdd(loss, 0.5f * s);
    __threadfence();
    unsigned old = atomicAdd(cnt, 1u);
    if (old == gridDim.x - 1) {
      float L = atomicAdd(loss, 0.f);  // device-coherent read
      out[BATCH] = L * (1e-6f / 4096.f);
    }
  }
}

extern "C" void kernel_launch(void* const* d_in, const int* in_sizes, int n_in,
                              void* d_out, int out_size, void* d_ws, size_t ws_size,
                              hipStream_t stream) {
  const int*   data      = (const int*)d_in[0];
  const int*   cell_nbr  = (const int*)d_in[1];
  const int*   drug_nbr  = (const int*)d_in[2];
  const float* protein   = (const float*)d_in[3];
  const float* cell_pre  = (const float*)d_in[4];
  const float* drug_pre  = (const float*)d_in[5];
  const float* w1        = (const float*)d_in[6];
  const float* b1        = (const float*)d_in[7];
  const float* w2        = (const float*)d_in[8];
  const float* b2        = (const float*)d_in[9];
  const float* out_w     = (const float*)d_in[10];
  const float* agg_w     = (const float*)d_in[12];
  const float* agg_b     = (const float*)d_in[13];
  const float* comb_w    = (const float*)d_in[14];
  float* out = (float*)d_out;
  char* base = (char*)d_ws;
  unsigned short* pool2h  = (unsigned short*)(base + POOL2H_B);
  unsigned short* pool2l  = (unsigned short*)(base + POOL2L_B);
  unsigned short* whi     = (unsigned short*)(base + WHI_B);
  unsigned short* wlo     = (unsigned short*)(base + WLO_B);
  float* xfc              = (float*)(base + XFC_B);
  float* item             = (float*)(base + ITEM_B);
  float* emb              = (float*)(base + EMB_B);
  float* V                = (float*)(base + V_B);
  float* loss             = (float*)(base + LOSS_B);
  unsigned* cnt           = (unsigned*)(base + CNT_B);
  bh8* ftab               = (bh8*)(base + FRAG_B);

  k_prep<<<1, 64, 0, stream>>>(w1, w2, b2, ftab, loss, cnt);
  k_conv12<<<dim3(4, 845), 512, 0, stream>>>(cell_pre, drug_pre, b1, out_w, ftab,
                                             pool2h, pool2l, whi, wlo, xfc);
  k_fc<<<dim3(53, 32), 64, 0, stream>>>(pool2h, pool2l, whi, wlo, xfc);
  k_norm<<<128, 256, 0, stream>>>(xfc, item);
  k_interact<<<840, 512, 0, stream>>>(cell_nbr, drug_nbr, protein, item, agg_w, agg_b,
                                      comb_w, emb, V);
  k_scoreall<<<70, 512, 0, stream>>>(data, cell_nbr, drug_nbr, protein, emb, V, out, loss, cnt);
}